// Round 7
// baseline (668.391 us; speedup 1.0000x reference)
//
#include <hip/hip_runtime.h>
#include <hip/hip_bf16.h>
#include <math.h>

#define BB 8
#define KK 256
#define DD 256
#define TT 2048
#define NH 4
#define HD 64
#define FW 8
#define FC 8
#define TPB 8     // t-rows per block in k4 (two groups of 4)
#define NK2 1056  // augmented K for final GEMM: 1024 attn + 8 EIN + 24 pad

// workspace float offsets
#define OFF_S    0
#define OFF_E    (OFF_S + BB*KK)                  // 2048
#define OFF_V    (OFF_E + BB*KK)                  // 4096
#define OFF_WC   (OFF_V + BB*KK*DD)               // 528384
#define OFF_CC   (OFF_WC + BB*KK*FW)              // 544768
#define OFF_C0   (OFF_CC + BB*KK*FC)              // 561152
#define OFF_W1T  (OFF_C0 + DD)                    // 561408
#define OFF_W2T  (OFF_W1T + DD*DD)                // 626944
#define OFF_U2B  (OFF_W2T + DD*DD)                // 692480  (bf16: 8 x 256 x 1056 shorts)
#define OFF_EINB (OFF_U2B + BB*DD*NK2/2)          // 1773824 (bf16: 8 x 2048 x 32 shorts)

// output float offsets (out, d, attn concatenated)
#define OUT_OUT  0
#define OUT_D    (BB*TT*DD)
#define OUT_ATTN (OUT_D + BB*KK)

typedef __attribute__((ext_vector_type(8))) short s8v;
typedef __attribute__((ext_vector_type(4))) float f4v;
typedef __attribute__((ext_vector_type(2))) _Float16 h2v;
typedef unsigned short ushort_t;

#define BC(x) __builtin_bit_cast(h2v, (unsigned int)(x))

__device__ __forceinline__ h2v pk(float a, float b) {
    return __builtin_bit_cast(h2v, __builtin_amdgcn_cvt_pkrtz(a, b));
}
__device__ __forceinline__ ushort_t f2bf(float x) {
    unsigned u = __float_as_uint(x);
    u += 0x7fffu + ((u >> 16) & 1u);
    return (ushort_t)(u >> 16);
}

#if __has_builtin(__builtin_amdgcn_fdot2)
#define FDOT2(a,b,c) __builtin_amdgcn_fdot2((a),(b),(c),false)
#else
__device__ __forceinline__ float FDOT2(h2v a, h2v b, float c) {
    return c + (float)a[0]*(float)b[0] + (float)a[1]*(float)b[1];
}
#endif

__device__ __forceinline__ float siluf(float z) {
    return z * __builtin_amdgcn_rcpf(1.0f + __expf(-z));
}

// ---- pure-DPP wave64 reductions: result in lane 63 ----
__device__ __forceinline__ float rsum64d(float x) {
    x += __int_as_float(__builtin_amdgcn_update_dpp(0, __float_as_int(x), 0x111, 0xf, 0xf, true));
    x += __int_as_float(__builtin_amdgcn_update_dpp(0, __float_as_int(x), 0x112, 0xf, 0xf, true));
    x += __int_as_float(__builtin_amdgcn_update_dpp(0, __float_as_int(x), 0x114, 0xf, 0xf, true));
    x += __int_as_float(__builtin_amdgcn_update_dpp(0, __float_as_int(x), 0x118, 0xf, 0xf, true));
    x += __int_as_float(__builtin_amdgcn_update_dpp(0, __float_as_int(x), 0x142, 0xa, 0xf, true));
    x += __int_as_float(__builtin_amdgcn_update_dpp(0, __float_as_int(x), 0x143, 0xc, 0xf, true));
    return x;
}
__device__ __forceinline__ float rmax64d(float x) {
    const int NI = 0xff800000;
    x = fmaxf(x, __int_as_float(__builtin_amdgcn_update_dpp(NI, __float_as_int(x), 0x111, 0xf, 0xf, false)));
    x = fmaxf(x, __int_as_float(__builtin_amdgcn_update_dpp(NI, __float_as_int(x), 0x112, 0xf, 0xf, false)));
    x = fmaxf(x, __int_as_float(__builtin_amdgcn_update_dpp(NI, __float_as_int(x), 0x114, 0xf, 0xf, false)));
    x = fmaxf(x, __int_as_float(__builtin_amdgcn_update_dpp(NI, __float_as_int(x), 0x118, 0xf, 0xf, false)));
    x = fmaxf(x, __int_as_float(__builtin_amdgcn_update_dpp(NI, __float_as_int(x), 0x142, 0xa, 0xf, false)));
    x = fmaxf(x, __int_as_float(__builtin_amdgcn_update_dpp(NI, __float_as_int(x), 0x143, 0xc, 0xf, false)));
    return x;
}
__device__ __forceinline__ float lane63f(float x) {
    return __int_as_float(__builtin_amdgcn_readlane(__float_as_int(x), 63));
}

// ---------------- prep: roles = {W1T(16), W2T(16), k1(8), R/C0/U2tail(8)} ----------------
__launch_bounds__(256)
__global__ void prep(const float* __restrict__ W1, const float* __restrict__ W2,
                     const float* __restrict__ phs, const float* __restrict__ Wd,
                     const float* __restrict__ bd,
                     const float* __restrict__ ceW, const float* __restrict__ ceb,
                     const float* __restrict__ W3, const float* __restrict__ b3,
                     const float* __restrict__ b2,
                     float* __restrict__ ws, float* __restrict__ dout) {
    __shared__ float tl[64][65];
    __shared__ float dbuf[KK];
    int role = blockIdx.x, tid = threadIdx.x;
    if (role < 32) {
        // 64x64 transpose tile
        const float* src = (role < 16) ? W1 : W2;
        float* dst = ws + ((role < 16) ? OFF_W1T : OFF_W2T);
        int rr = role & 15;
        int r0 = (rr >> 2)*64, c0 = (rr & 3)*64;
        int rx = tid >> 4, col4 = (tid & 15)*4;
#pragma unroll
        for (int i = 0; i < 4; ++i) {
            int row = rx + i*16;
            float4 vld = *(const float4*)&src[(size_t)(r0+row)*256 + c0 + col4];
            tl[row][col4+0]=vld.x; tl[row][col4+1]=vld.y; tl[row][col4+2]=vld.z; tl[row][col4+3]=vld.w;
        }
        __syncthreads();
#pragma unroll
        for (int i = 0; i < 4; ++i) {
            int row = rx + i*16;
            float4 vst;
            vst.x = tl[col4+0][row]; vst.y = tl[col4+1][row];
            vst.z = tl[col4+2][row]; vst.w = tl[col4+3][row];
            *(float4*)&dst[(size_t)(c0+row)*256 + r0 + col4] = vst;
        }
    } else if (role < 40) {
        // duration + cumsum for b
        int b = role - 32;
        int wave = tid >> 6, lane = tid & 63;
        float4 w4 = ((const float4*)Wd)[lane];
        float bd0 = bd[0];
        for (int kk = 0; kk < 64; ++kk) {
            int k = wave*64 + kk;
            float4 p = ((const float4*)(phs + (size_t)(b*KK + k)*DD))[lane];
            float part = p.x*w4.x + p.y*w4.y + p.z*w4.z + p.w*w4.w;
            float tot = rsum64d(part);
            if (lane == 63) {
                float acc = tot + bd0;
                float dl = fmaxf(acc, 0.f);
                dbuf[k] = fmaxf(expf(dl) - 1.f, 1e-12f);
            }
        }
        __syncthreads();
        int k = tid;
        float dv = dbuf[k];
        for (int off = 1; off < KK; off <<= 1) {
            float t = (k >= off) ? dbuf[k-off] : 0.f;
            __syncthreads();
            dbuf[k] += t;
            __syncthreads();
        }
        float e = dbuf[k];
        dout[OUT_D + b*KK + k] = dv;
        ws[OFF_S + b*KK + k] = e - dv;
        ws[OFF_E + b*KK + k] = e;
    } else {
        // R[j][c], C0[c], write U2 bf16 tail for b
        int b = role - 40, c = tid;
        float acc[8] = {0,0,0,0,0,0,0,0};
        float c0v = b3[c] + b2[c];
#pragma unroll 4
        for (int h = 0; h < NH; ++h) {
            for (int d = 0; d < HD; ++d) {
                float w3v = W3[(size_t)(h*HD + d)*DD + c];
                acc[h*2+0] = fmaf(ceW[d],      w3v, acc[h*2+0]);
                acc[h*2+1] = fmaf(ceW[HD + d], w3v, acc[h*2+1]);
                c0v        = fmaf(ceb[d],      w3v, c0v);
            }
        }
        ushort_t* rowp = (ushort_t*)(ws + OFF_U2B) + ((size_t)b*DD + c)*NK2 + 1024;
#pragma unroll
        for (int j = 0; j < 8; ++j) rowp[j] = f2bf(acc[j]);
#pragma unroll
        for (int j = 8; j < 32; ++j) rowp[j] = 0;
        if (b == 0) ws[OFF_C0 + c] = c0v;
    }
}

// ---------------- k3: fused conv + LN + SiLU (both paths via grid.y) ----------------
__launch_bounds__(256)
__global__ void k3(const float* __restrict__ vsrc, const float* __restrict__ wk,
                   const float* __restrict__ ck,
                   const float* __restrict__ wb, const float* __restrict__ wg,
                   const float* __restrict__ wbe,
                   const float* __restrict__ cb, const float* __restrict__ cg,
                   const float* __restrict__ cbe,
                   float* __restrict__ ws_) {
    __shared__ float vt[KK][33];
    __shared__ float wl[32][3][8];
    int b = blockIdx.x, ph = blockIdx.y;
    const float* kern = ph ? ck : wk;
    int tid = threadIdx.x, k = tid;
    bool hm = (k > 0), hp = (k < KK-1);
    float y[8] = {0,0,0,0,0,0,0,0};
    for (int ch = 0; ch < 8; ++ch) {
        int c0 = ch*32;
        __syncthreads();
        for (int i = tid; i < 768; i += 256) {
            int f = i & 7;
            int cq = i >> 3; int q = cq % 3; int cc = cq / 3;
            wl[cc][q][f] = kern[(f*DD + c0 + cc)*3 + q];
        }
        {
            int cc = tid & 31, r8 = tid >> 5;
            for (int j = 0; j < 32; ++j) {
                int row = r8 + j*8;
                vt[row][cc] = vsrc[(size_t)(b*KK + row)*DD + c0 + cc];
            }
        }
        __syncthreads();
        for (int cc = 0; cc < 32; ++cc) {
            float xm = hm ? vt[k-1][cc] : 0.f;
            float x0 = vt[k][cc];
            float xp = hp ? vt[k+1][cc] : 0.f;
            float4 a0 = *(const float4*)&wl[cc][0][0];
            float4 a1 = *(const float4*)&wl[cc][0][4];
            float4 b0 = *(const float4*)&wl[cc][1][0];
            float4 b1 = *(const float4*)&wl[cc][1][4];
            float4 c0v = *(const float4*)&wl[cc][2][0];
            float4 c1v = *(const float4*)&wl[cc][2][4];
            y[0] = fmaf(xm, a0.x, fmaf(x0, b0.x, fmaf(xp, c0v.x, y[0])));
            y[1] = fmaf(xm, a0.y, fmaf(x0, b0.y, fmaf(xp, c0v.y, y[1])));
            y[2] = fmaf(xm, a0.z, fmaf(x0, b0.z, fmaf(xp, c0v.z, y[2])));
            y[3] = fmaf(xm, a0.w, fmaf(x0, b0.w, fmaf(xp, c0v.w, y[3])));
            y[4] = fmaf(xm, a1.x, fmaf(x0, b1.x, fmaf(xp, c1v.x, y[4])));
            y[5] = fmaf(xm, a1.y, fmaf(x0, b1.y, fmaf(xp, c1v.y, y[5])));
            y[6] = fmaf(xm, a1.z, fmaf(x0, b1.z, fmaf(xp, c1v.z, y[6])));
            y[7] = fmaf(xm, a1.w, fmaf(x0, b1.w, fmaf(xp, c1v.w, y[7])));
        }
    }
    const float* bias = ph ? cb : wb;
    const float* g    = ph ? cg : wg;
    const float* beta = ph ? cbe : wbe;
#pragma unroll
    for (int f = 0; f < 8; ++f) y[f] += bias[f];
    float mu = 0.f;
#pragma unroll
    for (int f = 0; f < 8; ++f) mu += y[f];
    mu *= 0.125f;
    float var = 0.f;
#pragma unroll
    for (int f = 0; f < 8; ++f) { float dd = y[f]-mu; var = fmaf(dd, dd, var); }
    var *= 0.125f;
    float inv = rsqrtf(var + 1e-5f);
    float* dst = ws_ + (ph ? OFF_CC : OFF_WC) + (size_t)(b*KK + k)*8;
#pragma unroll
    for (int f = 0; f < 8; ++f) {
        float z = (y[f]-mu)*inv*g[f] + beta[f];
        dst[f] = siluf(z);
    }
}

// ---------------- k4: per-position MLPs + softmax + EIN(bf16) ----------------
__launch_bounds__(256, 3)
__global__ void k4_main(const float* __restrict__ ws, const int* __restrict__ tdur,
                        const float* __restrict__ sw1W, const float* __restrict__ sw1b,
                        const float* __restrict__ sw2W, const float* __restrict__ sw2b,
                        const float* __restrict__ weW, const float* __restrict__ web,
                        const float* __restrict__ sc1W, const float* __restrict__ sc1b,
                        const float* __restrict__ sc2W, const float* __restrict__ sc2b,
                        float* __restrict__ dout, ushort_t* __restrict__ einb) {
    __shared__ float sw1s[160];
    __shared__ float sw1bs[16];
    __shared__ float sc1s[20];
    __shared__ float sc1bs[2];
    __shared__ h2v   sw2h[16][8];
    __shared__ float sw2bias[16];
    __shared__ float wes4[16][4];
    __shared__ float webs[4], sc2s[4], sc2bs[2];
    __shared__ float red[4][4][16];
    __shared__ float gbuf[4][4][4];
    int tid = threadIdx.x;
    int b = blockIdx.y;
    int t0 = blockIdx.x * TPB;
    int lane = tid & 63, wid = tid >> 6;

    if (tid < 160) sw1s[tid] = sw1W[tid];
    if (tid < 16)  { sw1bs[tid] = sw1b[tid]; sw2bias[tid] = sw2b[tid]; }
    if (tid < 20)  sc1s[tid] = sc1W[tid];
    if (tid < 2)   { sc1bs[tid] = sc1b[tid]; sc2bs[tid] = sc2b[tid]; }
    if (tid < 4)   { webs[tid] = web[tid]; sc2s[tid] = sc2W[tid]; }
    if (tid < 128) {
        int j = tid >> 3, ip = tid & 7;
        sw2h[j][ip] = pk(sw2W[(2*ip)*16 + j], sw2W[(2*ip+1)*16 + j]);
    }
    if (tid < 64) wes4[tid>>2][tid&3] = weW[tid];
    __syncthreads();

    int k = tid;
    float s_k = ws[OFF_S + b*KK + k];
    float e_k = ws[OFF_E + b*KK + k];
    float al[16], be[16];
    float lgm[4], p2m[2];
    {
        float wcf[8];
        const float* wp = ws + OFF_WC + (size_t)(b*KK + k)*8;
#pragma unroll
        for (int f = 0; f < 8; ++f) wcf[f] = wp[f];
        float bw[16];
#pragma unroll
        for (int j = 0; j < 16; ++j) {
            float z = sw1bs[j];
#pragma unroll
            for (int f = 0; f < 8; ++f) z = fmaf(wcf[f], sw1s[(2+f)*16 + j], z);
            bw[j] = z;
        }
        h2v h1pm[8];
#pragma unroll
        for (int ip = 0; ip < 8; ++ip)
            h1pm[ip] = pk(siluf(bw[2*ip]), siluf(bw[2*ip+1]));
        lgm[0]=webs[0]; lgm[1]=webs[1]; lgm[2]=webs[2]; lgm[3]=webs[3];
#pragma unroll
        for (int j = 0; j < 16; ++j) {
            const uint4* wpq = (const uint4*)&sw2h[j][0];
            uint4 wa = wpq[0], wb = wpq[1];
            float z = sw2bias[j];
            z = FDOT2(h1pm[0], BC(wa.x), z); z = FDOT2(h1pm[1], BC(wa.y), z);
            z = FDOT2(h1pm[2], BC(wa.z), z); z = FDOT2(h1pm[3], BC(wa.w), z);
            z = FDOT2(h1pm[4], BC(wb.x), z); z = FDOT2(h1pm[5], BC(wb.y), z);
            z = FDOT2(h1pm[6], BC(wb.z), z); z = FDOT2(h1pm[7], BC(wb.w), z);
            float g = siluf(z);
            float4 wv = *(const float4*)&wes4[j][0];
            lgm[0] = fmaf(g, wv.x, lgm[0]); lgm[1] = fmaf(g, wv.y, lgm[1]);
            lgm[2] = fmaf(g, wv.z, lgm[2]); lgm[3] = fmaf(g, wv.w, lgm[3]);
        }
#pragma unroll
        for (int j = 0; j < 16; ++j) {
            float wsj = sw1s[j], wej = sw1s[16 + j];
            be[j] = wsj - wej;
            al[j] = bw[j] - wsj*s_k + wej*e_k;
        }
    }
    float gc[2], dc[2];
    {
        float ccf[8];
        const float* cp = ws + OFF_CC + (size_t)(b*KK + k)*8;
#pragma unroll
        for (int f = 0; f < 8; ++f) ccf[f] = cp[f];
        float bc0 = sc1bs[0], bc1 = sc1bs[1];
#pragma unroll
        for (int f = 0; f < 8; ++f) {
            bc0 = fmaf(ccf[f], sc1s[(2+f)*2 + 0], bc0);
            bc1 = fmaf(ccf[f], sc1s[(2+f)*2 + 1], bc1);
        }
        gc[0] = sc1s[0] - sc1s[2]; gc[1] = sc1s[1] - sc1s[3];
        dc[0] = bc0 - sc1s[0]*s_k + sc1s[2]*e_k;
        dc[1] = bc1 - sc1s[1]*s_k + sc1s[3]*e_k;
        float p1m0 = siluf(bc0), p1m1 = siluf(bc1);
        p2m[0] = siluf(p1m0*sc2s[0] + p1m1*sc2s[2] + sc2bs[0]);
        p2m[1] = siluf(p1m0*sc2s[1] + p1m1*sc2s[3] + sc2bs[1]);
    }
    float sc2r0 = sc2s[0], sc2r1 = sc2s[1], sc2r2 = sc2s[2], sc2r3 = sc2s[3];
    float sc2b0 = sc2bs[0], sc2b1 = sc2bs[1];
    float web0 = webs[0], web1 = webs[1], web2 = webs[2], web3 = webs[3];
    int td = tdur[b];

    for (int tg = 0; tg < TPB; tg += 4) {
        int tbase = t0 + tg;
        h2v h1p[4][8];
        float p2v[4][2];
        float lg[4][4];
        float ex[4][4];
#pragma unroll
        for (int u = 0; u < 4; ++u) {
            float tp1 = (float)(tbase + u + 1);
#pragma unroll
            for (int ip = 0; ip < 8; ++ip) {
                float z0 = siluf(fmaf(tp1, be[2*ip], al[2*ip]));
                float z1 = siluf(fmaf(tp1, be[2*ip+1], al[2*ip+1]));
                h1p[u][ip] = pk(z0, z1);
            }
            float p10 = siluf(fmaf(tp1, gc[0], dc[0]));
            float p11 = siluf(fmaf(tp1, gc[1], dc[1]));
            p2v[u][0] = siluf(p10*sc2r0 + p11*sc2r2 + sc2b0);
            p2v[u][1] = siluf(p10*sc2r1 + p11*sc2r3 + sc2b1);
            lg[u][0]=web0; lg[u][1]=web1; lg[u][2]=web2; lg[u][3]=web3;
        }
#pragma unroll
        for (int j = 0; j < 16; ++j) {
            const uint4* wpq = (const uint4*)&sw2h[j][0];
            uint4 wa = wpq[0], wb = wpq[1];
            h2v w0=BC(wa.x), w1=BC(wa.y), w2=BC(wa.z), w3=BC(wa.w);
            h2v w4_=BC(wb.x), w5=BC(wb.y), w6=BC(wb.z), w7=BC(wb.w);
            float bias = sw2bias[j];
            float4 wv = *(const float4*)&wes4[j][0];
#pragma unroll
            for (int u = 0; u < 4; ++u) {
                float z = bias;
                z = FDOT2(h1p[u][0], w0, z); z = FDOT2(h1p[u][1], w1, z);
                z = FDOT2(h1p[u][2], w2, z); z = FDOT2(h1p[u][3], w3, z);
                z = FDOT2(h1p[u][4], w4_, z); z = FDOT2(h1p[u][5], w5, z);
                z = FDOT2(h1p[u][6], w6, z); z = FDOT2(h1p[u][7], w7, z);
                float g = siluf(z);
                lg[u][0] = fmaf(g, wv.x, lg[u][0]);
                lg[u][1] = fmaf(g, wv.y, lg[u][1]);
                lg[u][2] = fmaf(g, wv.z, lg[u][2]);
                lg[u][3] = fmaf(g, wv.w, lg[u][3]);
            }
        }
#pragma unroll
        for (int u = 0; u < 4; ++u) {
            if ((tbase + u) >= td) {
                lg[u][0]=lgm[0]; lg[u][1]=lgm[1]; lg[u][2]=lgm[2]; lg[u][3]=lgm[3];
                p2v[u][0]=p2m[0]; p2v[u][1]=p2m[1];
            }
        }
#pragma unroll
        for (int u = 0; u < 4; ++u) {
            float m0 = lane63f(rmax64d(lg[u][0]));
            float m1 = lane63f(rmax64d(lg[u][1]));
            float m2 = lane63f(rmax64d(lg[u][2]));
            float m3 = lane63f(rmax64d(lg[u][3]));
            ex[u][0] = __expf(lg[u][0] - m0);
            ex[u][1] = __expf(lg[u][1] - m1);
            ex[u][2] = __expf(lg[u][2] - m2);
            ex[u][3] = __expf(lg[u][3] - m3);
            float s0 = rsum64d(ex[u][0]), s1 = rsum64d(ex[u][1]);
            float s2 = rsum64d(ex[u][2]), s3 = rsum64d(ex[u][3]);
            float u0 = rsum64d(ex[u][0]*p2v[u][0]);
            float u1 = rsum64d(ex[u][0]*p2v[u][1]);
            float u2 = rsum64d(ex[u][1]*p2v[u][0]);
            float u3 = rsum64d(ex[u][1]*p2v[u][1]);
            float u4 = rsum64d(ex[u][2]*p2v[u][0]);
            float u5 = rsum64d(ex[u][2]*p2v[u][1]);
            float u6 = rsum64d(ex[u][3]*p2v[u][0]);
            float u7 = rsum64d(ex[u][3]*p2v[u][1]);
            if (lane == 63) {
                float* rr = &red[u][wid][0];
                *(float4*)&rr[0]  = make_float4(m0, m1, m2, m3);
                *(float4*)&rr[4]  = make_float4(s0, s1, s2, s3);
                *(float4*)&rr[8]  = make_float4(u0, u1, u2, u3);
                *(float4*)&rr[12] = make_float4(u4, u5, u6, u7);
            }
        }
        __syncthreads();
        if (tid < 64) {
            int u = tid >> 4, h = (tid >> 2) & 3, w = tid & 3;
            float m0 = red[u][0][h], m1 = red[u][1][h], m2 = red[u][2][h], m3 = red[u][3][h];
            float M = fmaxf(fmaxf(m0, m1), fmaxf(m2, m3));
            float f0 = __expf(m0 - M), f1 = __expf(m1 - M);
            float f2 = __expf(m2 - M), f3 = __expf(m3 - M);
            float S = red[u][0][4+h]*f0 + red[u][1][4+h]*f1
                    + red[u][2][4+h]*f2 + red[u][3][4+h]*f3;
            float fw = (w == 0) ? f0 : ((w == 1) ? f1 : ((w == 2) ? f2 : f3));
            gbuf[u][w][h] = fw * __builtin_amdgcn_rcpf(S);
        } else if (tid < 96) {
            int idx = tid - 64, u = idx >> 3, j = idx & 7, h = j >> 1;
            float m0 = red[u][0][h], m1 = red[u][1][h], m2 = red[u][2][h], m3 = red[u][3][h];
            float M = fmaxf(fmaxf(m0, m1), fmaxf(m2, m3));
            float f0 = __expf(m0 - M), f1 = __expf(m1 - M);
            float f2 = __expf(m2 - M), f3 = __expf(m3 - M);
            float S = red[u][0][4+h]*f0 + red[u][1][4+h]*f1
                    + red[u][2][4+h]*f2 + red[u][3][4+h]*f3;
            float num = red[u][0][8+j]*f0 + red[u][1][8+j]*f1
                      + red[u][2][8+j]*f2 + red[u][3][8+j]*f3;
            einb[((size_t)b*TT + tbase + u)*32 + j] = f2bf(num * __builtin_amdgcn_rcpf(S));
        } else if (tid < 192) {
            int idx = tid - 96, u = idx / 24, r = idx - u*24;
            einb[((size_t)b*TT + tbase + u)*32 + 8 + r] = 0;
        }
        __syncthreads();
#pragma unroll
        for (int u = 0; u < 4; ++u) {
            int t = tbase + u;
            float4 g4 = *(const float4*)&gbuf[u][wid][0];
            dout[OUT_ATTN + ((size_t)(b*NH + 0)*TT + t)*KK + k] = ex[u][0] * g4.x;
            dout[OUT_ATTN + ((size_t)(b*NH + 1)*TT + t)*KK + k] = ex[u][1] * g4.y;
            dout[OUT_ATTN + ((size_t)(b*NH + 2)*TT + t)*KK + k] = ex[u][2] * g4.z;
            dout[OUT_ATTN + ((size_t)(b*NH + 3)*TT + t)*KK + k] = ex[u][3] * g4.w;
        }
    }
}

// ---------------- kmm: C[m,n] = sum_k A[m,k]*B[n,k] (+bias[n]), f32 out ----------------
#define MLDA 56
__launch_bounds__(256, 2)
__global__ void kmm(const float* __restrict__ A, const float* __restrict__ B,
                    float* __restrict__ C, const float* __restrict__ bias,
                    int Kd, int lda, int ldb, int ldc) {
    int m0 = blockIdx.x * 128, n0 = blockIdx.y * 128;
    __shared__ ushort_t Asl[128*MLDA];
    __shared__ ushort_t Bsl[128*MLDA];
    int tid = threadIdx.x;
    int lane = tid & 63, wid = tid >> 6;
    int wm = wid & 1, wn = wid >> 1;
    int quad = lane >> 4, lo = lane & 15;
    f4v acc[4][4];
#pragma unroll
    for (int i = 0; i < 4; ++i)
#pragma unroll
        for (int j = 0; j < 4; ++j) { f4v zz = {0.f,0.f,0.f,0.f}; acc[i][j] = zz; }
    int srow = tid >> 3;
    int scol = (tid & 7) * 4;
    for (int k0 = 0; k0 < Kd; k0 += 32) {
#pragma unroll
        for (int i = 0; i < 4; ++i) {
            int r = srow + i*32;
            float4 va = *(const float4*)&A[(size_t)(m0 + r)*lda + k0 + scol];
            float4 vb = *(const float4*)&B[(size_t)(n0 + r)*ldb + k0 + scol];
            __hip_bfloat162 pa0 = __float22bfloat162_rn(make_float2(va.x, va.y));
            __hip_bfloat162 pa1 = __float22bfloat162_rn(make_float2(va.z, va.w));
            __hip_bfloat162 pb0 = __float22bfloat162_rn(make_float2(vb.x, vb.y));
            __hip_bfloat162 pb1 = __float22bfloat162_rn(make_float2(vb.z, vb.w));
            *(uint2*)&Asl[r*MLDA + scol] = make_uint2(*(unsigned int*)&pa0, *(unsigned int*)&pa1);
            *(uint2*)&Bsl[r*MLDA + scol] = make_uint2(*(unsigned int*)&pb0, *(unsigned int*)&pb1);
        }
        __syncthreads();
        s8v af[4], bf[4];
#pragma unroll
        for (int mt = 0; mt < 4; ++mt)
            af[mt] = *(const s8v*)&Asl[(wm*64 + mt*16 + lo)*MLDA + quad*8];
#pragma unroll
        for (int nt = 0; nt < 4; ++nt)
            bf[nt] = *(const s8v*)&Bsl[(wn*64 + nt*16 + lo)*MLDA + quad*8];
#pragma unroll
        for (int mt = 0; mt < 4; ++mt)
#pragma unroll
            for (int nt = 0; nt < 4; ++nt)
                acc[mt][nt] = __builtin_amdgcn_mfma_f32_16x16x32_bf16(af[mt], bf[nt], acc[mt][nt], 0, 0, 0);
        __syncthreads();
    }
#pragma unroll
    for (int mt = 0; mt < 4; ++mt)
#pragma unroll
        for (int nt = 0; nt < 4; ++nt) {
            int col = n0 + wn*64 + nt*16 + lo;
            float bv = bias ? bias[col] : 0.f;
#pragma unroll
            for (int r = 0; r < 4; ++r) {
                int row = m0 + wm*64 + mt*16 + quad*4 + r;
                C[(size_t)row*ldc + col] = acc[mt][nt][r] + bv;
            }
        }
}

// ---------------- kmmB: same but bf16 output (U2 build), batched z=(b,h) ----------------
__launch_bounds__(256, 2)
__global__ void kmmB(const float* __restrict__ A, const float* __restrict__ B,
                     ushort_t* __restrict__ C,
                     int Kd, int lda, int ldb, int ldc,
                     long sA2, long sB1, long sB2, long sC1, long sC2, int nz2) {
    int z = blockIdx.z, z1 = z / nz2, z2 = z - z1*nz2;
    A += (size_t)z2*sA2;
    B += (size_t)z1*sB1 + (size_t)z2*sB2;
    C += (size_t)z1*sC1 + (size_t)z2*sC2;
    int m0 = blockIdx.x * 128, n0 = blockIdx.y * 128;
    __shared__ ushort_t Asl[128*MLDA];
    __shared__ ushort_t Bsl[128*MLDA];
    int tid = threadIdx.x;
    int lane = tid & 63, wid = tid >> 6;
    int wm = wid & 1, wn = wid >> 1;
    int quad = lane >> 4, lo = lane & 15;
    f4v acc[4][4];
#pragma unroll
    for (int i = 0; i < 4; ++i)
#pragma unroll
        for (int j = 0; j < 4; ++j) { f4v zz = {0.f,0.f,0.f,0.f}; acc[i][j] = zz; }
    int srow = tid >> 3;
    int scol = (tid & 7) * 4;
    for (int k0 = 0; k0 < Kd; k0 += 32) {
#pragma unroll
        for (int i = 0; i < 4; ++i) {
            int r = srow + i*32;
            float4 va = *(const float4*)&A[(size_t)(m0 + r)*lda + k0 + scol];
            float4 vb = *(const float4*)&B[(size_t)(n0 + r)*ldb + k0 + scol];
            __hip_bfloat162 pa0 = __float22bfloat162_rn(make_float2(va.x, va.y));
            __hip_bfloat162 pa1 = __float22bfloat162_rn(make_float2(va.z, va.w));
            __hip_bfloat162 pb0 = __float22bfloat162_rn(make_float2(vb.x, vb.y));
            __hip_bfloat162 pb1 = __float22bfloat162_rn(make_float2(vb.z, vb.w));
            *(uint2*)&Asl[r*MLDA + scol] = make_uint2(*(unsigned int*)&pa0, *(unsigned int*)&pa1);
            *(uint2*)&Bsl[r*MLDA + scol] = make_uint2(*(unsigned int*)&pb0, *(unsigned int*)&pb1);
        }
        __syncthreads();
        s8v af[4], bf[4];
#pragma unroll
        for (int mt = 0; mt < 4; ++mt)
            af[mt] = *(const s8v*)&Asl[(wm*64 + mt*16 + lo)*MLDA + quad*8];
#pragma unroll
        for (int nt = 0; nt < 4; ++nt)
            bf[nt] = *(const s8v*)&Bsl[(wn*64 + nt*16 + lo)*MLDA + quad*8];
#pragma unroll
        for (int mt = 0; mt < 4; ++mt)
#pragma unroll
            for (int nt = 0; nt < 4; ++nt)
                acc[mt][nt] = __builtin_amdgcn_mfma_f32_16x16x32_bf16(af[mt], bf[nt], acc[mt][nt], 0, 0, 0);
        __syncthreads();
    }
#pragma unroll
    for (int mt = 0; mt < 4; ++mt)
#pragma unroll
        for (int nt = 0; nt < 4; ++nt) {
            int col = n0 + wn*64 + nt*16 + lo;
#pragma unroll
            for (int r = 0; r < 4; ++r) {
                int row = m0 + wm*64 + mt*16 + quad*4 + r;
                C[(size_t)row*ldc + col] = f2bf(acc[mt][nt][r]);
            }
        }
}

// ---------------- kOL2: out = [attn(f32)|EIN(bf16)] @ U2(bf16) + C0 ----------------
__launch_bounds__(256, 2)
__global__ void kOL2(const float* __restrict__ attn, const ushort_t* __restrict__ einb,
                     const ushort_t* __restrict__ U2B, const float* __restrict__ C0,
                     float* __restrict__ out) {
    __shared__ ushort_t Asl[128*MLDA];
    __shared__ ushort_t Bsl[128*MLDA];
    int b = blockIdx.z;
    int t0 = blockIdx.x * 128, c0 = blockIdx.y * 128;
    int tid = threadIdx.x;
    int lane = tid & 63, wid = tid >> 6;
    int wm = wid & 1, wn = wid >> 1;
    int quad = lane >> 4, lo = lane & 15;
    f4v acc[4][4];
#pragma unroll
    for (int i = 0; i < 4; ++i)
#pragma unroll
        for (int j = 0; j < 4; ++j) { f4v zz = {0.f,0.f,0.f,0.f}; acc[i][j] = zz; }
    const float* Ab = attn + (size_t)b*NH*TT*KK;
    const ushort_t* Bb = U2B + (size_t)b*DD*NK2;
    int srow = tid >> 3;            // 0..31 (f32 A staging)
    int scol = (tid & 7) * 4;
    int rB = tid >> 2;              // 0..63 (bf16 staging)
    int cB = (tid & 3) * 8;
    for (int k0 = 0; k0 < NK2; k0 += 32) {
        if (k0 < NH*KK) {
            const float* ag = Ab + ((size_t)((k0 >> 8)*TT + t0))*KK + (k0 & 255);
#pragma unroll
            for (int i = 0; i < 4; ++i) {
                int r = srow + i*32;
                float4 va = *(const float4*)(ag + (size_t)r*KK + scol);
                __hip_bfloat162 pa0 = __float22bfloat162_rn(make_float2(va.x, va.y));
                __hip_bfloat162 pa1 = __float22bfloat162_rn(make_float2(va.z, va.w));
                *(uint2*)&Asl[r*MLDA + scol] = make_uint2(*(unsigned int*)&pa0, *(unsigned int*)&pa1);
            }
        } else {
            const ushort_t* ag = einb + ((size_t)b*TT + t0)*32;
#pragma unroll
            for (int i = 0; i < 2; ++i) {
                int r = rB + i*64;
                uint4 w = *(const uint4*)(ag + (size_t)r*32 + cB);
                *(uint4*)&Asl[r*MLDA + cB] = w;
            }
        }
        {
            const ushort_t* bg = Bb + (size_t)c0*NK2 + k0;
#pragma unroll
            for (int i = 0; i < 2; ++i) {
                int r = rB + i*64;
                uint4 w = *(const uint4*)(bg + (size_t)r*NK2 + cB);
                *(uint4*)&Bsl[r*MLDA + cB] = w;
            }
        }
        __syncthreads();
        s8v af[4], bf[4];
#pragma unroll
        for (int mt = 0; mt < 4; ++mt)
            af[mt] = *(const s8v*)&Asl[(wm*64 + mt*16 + lo)*MLDA + quad*8];
#pragma unroll
        for (int nt = 0; nt < 4; ++nt)
            bf[nt] = *(const s8v*)&Bsl[(wn*64 + nt*16 + lo)*MLDA + quad*8];
#pragma unroll
        for (int mt = 0; mt < 4; ++mt)
#pragma unroll
            for (int nt = 0; nt < 4; ++nt)
                acc[mt][nt] = __builtin_amdgcn_mfma_f32_16x16x32_bf16(af[mt], bf[nt], acc[mt][nt], 0, 0, 0);
        __syncthreads();
    }
#pragma unroll
    for (int mt = 0; mt < 4; ++mt)
#pragma unroll
        for (int nt = 0; nt < 4; ++nt) {
            int col = c0 + wn*64 + nt*16 + lo;
            float bv = C0[col];
#pragma unroll
            for (int r = 0; r < 4; ++r) {
                int row = t0 + wm*64 + mt*16 + quad*4 + r;
                out[((size_t)b*TT + row)*DD + col] = acc[mt][nt][r] + bv;
            }
        }
}

extern "C" void kernel_launch(void* const* d_in, const int* in_sizes, int n_in,
                              void* d_out, int out_size, void* d_ws, size_t ws_size,
                              hipStream_t stream) {
    const float* phs  = (const float*)d_in[0];
    const int*   tdur = (const int*)d_in[2];
    const float* Wd   = (const float*)d_in[4];
    const float* bd   = (const float*)d_in[5];
    const float* W1   = (const float*)d_in[6];
    const float* b1   = (const float*)d_in[7];
    const float* W2   = (const float*)d_in[8];
    const float* b2   = (const float*)d_in[9];
    const float* W3   = (const float*)d_in[10];
    const float* b3   = (const float*)d_in[11];
    const float* wck  = (const float*)d_in[12];
    const float* wcb  = (const float*)d_in[13];
    const float* wlg  = (const float*)d_in[14];
    const float* wlb  = (const float*)d_in[15];
    const float* cck  = (const float*)d_in[16];
    const float* ccb  = (const float*)d_in[17];
    const float* clg  = (const float*)d_in[18];
    const float* clb  = (const float*)d_in[19];
    const float* sw1W = (const float*)d_in[20];
    const float* sw1b = (const float*)d_in[21];
    const float* sw2W = (const float*)d_in[22];
    const float* sw2b = (const float*)d_in[23];
    const float* sc1W = (const float*)d_in[24];
    const float* sc1b = (const float*)d_in[25];
    const float* sc2W = (const float*)d_in[26];
    const float* sc2b = (const float*)d_in[27];
    const float* weW  = (const float*)d_in[28];
    const float* web  = (const float*)d_in[29];
    const float* ceW  = (const float*)d_in[30];
    const float* ceb  = (const float*)d_in[31];

    float* out = (float*)d_out;
    float* ws  = (float*)d_ws;
    ushort_t* U2B  = (ushort_t*)(ws + OFF_U2B);
    ushort_t* EINB = (ushort_t*)(ws + OFF_EINB);

    // 1) prep: W1T, W2T, duration/cumsum, R->U2 tail + C0
    prep<<<48, 256, 0, stream>>>(W1, W2, phs, Wd, bd, ceW, ceb, W3, b3, b2, ws, out);
    // 2) v = phs @ W1 + b1
    kmm<<<dim3(16,2,1), 256, 0, stream>>>(phs, ws + OFF_W1T, ws + OFF_V, b1,
        256, 256, 256, 256);
    // 3) conv features (fused conv+LN+SiLU)
    k3<<<dim3(BB,2), 256, 0, stream>>>(ws + OFF_V, wck, cck, wcb, wlg, wlb,
                                       ccb, clg, clb, ws);
    // 4) U2 bf16: U2[b, c, h*256+k] = sum_d W2T[c, h64+d] * v[b, k, h64+d]
    kmmB<<<dim3(2,2,32), 256, 0, stream>>>(ws + OFF_W2T, ws + OFF_V, U2B,
        64, 256, 256, NK2,
        64, (long)KK*DD, 64, (long)DD*NK2, 256, 4);
    // 5) main fused kernel: attn + EIN(bf16)
    k4_main<<<dim3(TT/TPB, BB), 256, 0, stream>>>(ws, tdur, sw1W, sw1b, sw2W, sw2b,
                                                  weW, web, sc1W, sc1b, sc2W, sc2b,
                                                  out, EINB);
    // 6) out = [attn|EIN] @ U2 + C0
    kOL2<<<dim3(TT/128, 2, BB), 256, 0, stream>>>(out + OUT_ATTN, EINB, U2B,
                                                  ws + OFF_C0, out);
}

// Round 8
// 376.025 us; speedup vs baseline: 1.7775x; 1.7775x over previous
//
#include <hip/hip_runtime.h>
#include <hip/hip_bf16.h>
#include <math.h>

#define BB 8
#define KK 256
#define DD 256
#define TT 2048
#define NH 4
#define HD 64
#define FW 8
#define FC 8
#define TPB 8     // t-rows per block in k4 (two groups of 4)
#define NK2 1056  // augmented K for final GEMM: 1024 attn + 8 EIN + 24 pad

// workspace float offsets
#define OFF_S    0
#define OFF_E    (OFF_S + BB*KK)                  // 2048
#define OFF_V    (OFF_E + BB*KK)                  // 4096
#define OFF_WC   (OFF_V + BB*KK*DD)               // 528384
#define OFF_CC   (OFF_WC + BB*KK*FW)              // 544768
#define OFF_C0   (OFF_CC + BB*KK*FC)              // 561152
#define OFF_W1T  (OFF_C0 + DD)                    // 561408
#define OFF_W2T  (OFF_W1T + DD*DD)                // 626944
#define OFF_U2B  (OFF_W2T + DD*DD)                // 692480  (bf16: 8 x 256 x 1056 shorts)
#define OFF_EINB (OFF_U2B + BB*DD*NK2/2)          // 1773824 (bf16: 8 x 2048 x 32 shorts)
#define OFF_P3   (OFF_EINB + BB*TT*32/2)          // 2035968 (conv partials, 8x2x8x256x8 f32)

// output float offsets (out, d, attn concatenated)
#define OUT_OUT  0
#define OUT_D    (BB*TT*DD)
#define OUT_ATTN (OUT_D + BB*KK)

typedef __attribute__((ext_vector_type(8))) short s8v;
typedef __attribute__((ext_vector_type(4))) float f4v;
typedef __attribute__((ext_vector_type(2))) _Float16 h2v;
typedef unsigned short ushort_t;

#define BC(x) __builtin_bit_cast(h2v, (unsigned int)(x))

__device__ __forceinline__ h2v pk(float a, float b) {
    return __builtin_bit_cast(h2v, __builtin_amdgcn_cvt_pkrtz(a, b));
}
__device__ __forceinline__ ushort_t f2bf(float x) {
    unsigned u = __float_as_uint(x);
    u += 0x7fffu + ((u >> 16) & 1u);
    return (ushort_t)(u >> 16);
}

#if __has_builtin(__builtin_amdgcn_fdot2)
#define FDOT2(a,b,c) __builtin_amdgcn_fdot2((a),(b),(c),false)
#else
__device__ __forceinline__ float FDOT2(h2v a, h2v b, float c) {
    return c + (float)a[0]*(float)b[0] + (float)a[1]*(float)b[1];
}
#endif

__device__ __forceinline__ float siluf(float z) {
    return z * __builtin_amdgcn_rcpf(1.0f + __expf(-z));
}

// ---- pure-DPP wave64 reductions: result in lane 63 ----
__device__ __forceinline__ float rsum64d(float x) {
    x += __int_as_float(__builtin_amdgcn_update_dpp(0, __float_as_int(x), 0x111, 0xf, 0xf, true));
    x += __int_as_float(__builtin_amdgcn_update_dpp(0, __float_as_int(x), 0x112, 0xf, 0xf, true));
    x += __int_as_float(__builtin_amdgcn_update_dpp(0, __float_as_int(x), 0x114, 0xf, 0xf, true));
    x += __int_as_float(__builtin_amdgcn_update_dpp(0, __float_as_int(x), 0x118, 0xf, 0xf, true));
    x += __int_as_float(__builtin_amdgcn_update_dpp(0, __float_as_int(x), 0x142, 0xa, 0xf, true));
    x += __int_as_float(__builtin_amdgcn_update_dpp(0, __float_as_int(x), 0x143, 0xc, 0xf, true));
    return x;
}
__device__ __forceinline__ float rmax64d(float x) {
    const int NI = 0xff800000;
    x = fmaxf(x, __int_as_float(__builtin_amdgcn_update_dpp(NI, __float_as_int(x), 0x111, 0xf, 0xf, false)));
    x = fmaxf(x, __int_as_float(__builtin_amdgcn_update_dpp(NI, __float_as_int(x), 0x112, 0xf, 0xf, false)));
    x = fmaxf(x, __int_as_float(__builtin_amdgcn_update_dpp(NI, __float_as_int(x), 0x114, 0xf, 0xf, false)));
    x = fmaxf(x, __int_as_float(__builtin_amdgcn_update_dpp(NI, __float_as_int(x), 0x118, 0xf, 0xf, false)));
    x = fmaxf(x, __int_as_float(__builtin_amdgcn_update_dpp(NI, __float_as_int(x), 0x142, 0xa, 0xf, false)));
    x = fmaxf(x, __int_as_float(__builtin_amdgcn_update_dpp(NI, __float_as_int(x), 0x143, 0xc, 0xf, false)));
    return x;
}
__device__ __forceinline__ float lane63f(float x) {
    return __int_as_float(__builtin_amdgcn_readlane(__float_as_int(x), 63));
}

// ---------------- prep: roles = {W1T(16), W2T(16), k1(8), R/C0/U2tail(8)} ----------------
__launch_bounds__(256)
__global__ void prep(const float* __restrict__ W1, const float* __restrict__ W2,
                     const float* __restrict__ phs, const float* __restrict__ Wd,
                     const float* __restrict__ bd,
                     const float* __restrict__ ceW, const float* __restrict__ ceb,
                     const float* __restrict__ W3, const float* __restrict__ b3,
                     const float* __restrict__ b2,
                     float* __restrict__ ws, float* __restrict__ dout) {
    __shared__ float tl[64][65];
    __shared__ float dbuf[KK];
    int role = blockIdx.x, tid = threadIdx.x;
    if (role < 32) {
        const float* src = (role < 16) ? W1 : W2;
        float* dst = ws + ((role < 16) ? OFF_W1T : OFF_W2T);
        int rr = role & 15;
        int r0 = (rr >> 2)*64, c0 = (rr & 3)*64;
        int rx = tid >> 4, col4 = (tid & 15)*4;
#pragma unroll
        for (int i = 0; i < 4; ++i) {
            int row = rx + i*16;
            float4 vld = *(const float4*)&src[(size_t)(r0+row)*256 + c0 + col4];
            tl[row][col4+0]=vld.x; tl[row][col4+1]=vld.y; tl[row][col4+2]=vld.z; tl[row][col4+3]=vld.w;
        }
        __syncthreads();
#pragma unroll
        for (int i = 0; i < 4; ++i) {
            int row = rx + i*16;
            float4 vst;
            vst.x = tl[col4+0][row]; vst.y = tl[col4+1][row];
            vst.z = tl[col4+2][row]; vst.w = tl[col4+3][row];
            *(float4*)&dst[(size_t)(c0+row)*256 + r0 + col4] = vst;
        }
    } else if (role < 40) {
        int b = role - 32;
        int wave = tid >> 6, lane = tid & 63;
        float4 w4 = ((const float4*)Wd)[lane];
        float bd0 = bd[0];
        for (int kk = 0; kk < 64; ++kk) {
            int k = wave*64 + kk;
            float4 p = ((const float4*)(phs + (size_t)(b*KK + k)*DD))[lane];
            float part = p.x*w4.x + p.y*w4.y + p.z*w4.z + p.w*w4.w;
            float tot = rsum64d(part);
            if (lane == 63) {
                float acc = tot + bd0;
                float dl = fmaxf(acc, 0.f);
                dbuf[k] = fmaxf(expf(dl) - 1.f, 1e-12f);
            }
        }
        __syncthreads();
        int k = tid;
        float dv = dbuf[k];
        for (int off = 1; off < KK; off <<= 1) {
            float t = (k >= off) ? dbuf[k-off] : 0.f;
            __syncthreads();
            dbuf[k] += t;
            __syncthreads();
        }
        float e = dbuf[k];
        dout[OUT_D + b*KK + k] = dv;
        ws[OFF_S + b*KK + k] = e - dv;
        ws[OFF_E + b*KK + k] = e;
    } else {
        int b = role - 40, c = tid;
        float acc[8] = {0,0,0,0,0,0,0,0};
        float c0v = b3[c] + b2[c];
#pragma unroll 4
        for (int h = 0; h < NH; ++h) {
            for (int d = 0; d < HD; ++d) {
                float w3v = W3[(size_t)(h*HD + d)*DD + c];
                acc[h*2+0] = fmaf(ceW[d],      w3v, acc[h*2+0]);
                acc[h*2+1] = fmaf(ceW[HD + d], w3v, acc[h*2+1]);
                c0v        = fmaf(ceb[d],      w3v, c0v);
            }
        }
        ushort_t* rowp = (ushort_t*)(ws + OFF_U2B) + ((size_t)b*DD + c)*NK2 + 1024;
#pragma unroll
        for (int j = 0; j < 8; ++j) rowp[j] = f2bf(acc[j]);
#pragma unroll
        for (int j = 8; j < 32; ++j) rowp[j] = 0;
        if (b == 0) ws[OFF_C0 + c] = c0v;
    }
}

// ---------------- k3a: conv partials, LDS-staged (proven R6 form) ----------------
__launch_bounds__(256)
__global__ void k3a(const float* __restrict__ vsrc, const float* __restrict__ wk,
                    const float* __restrict__ ck, float* __restrict__ part) {
    __shared__ float vt[KK][33];
    __shared__ float wl[32][3][8];
    int b = blockIdx.x, ch = blockIdx.y, ph = blockIdx.z;
    const float* kern = ph ? ck : wk;
    int tid = threadIdx.x, c0 = ch*32;
    for (int i = tid; i < 768; i += 256) {
        int f = i & 7;
        int cq = i >> 3; int q = cq % 3; int cc = cq / 3;
        wl[cc][q][f] = kern[(f*DD + c0 + cc)*3 + q];
    }
    {
        int cc = tid & 31, r8 = tid >> 5;
        for (int j = 0; j < 32; ++j) {
            int row = r8 + j*8;
            vt[row][cc] = vsrc[(size_t)(b*KK + row)*DD + c0 + cc];
        }
    }
    __syncthreads();
    int k = tid;
    float y[8] = {0.f,0.f,0.f,0.f,0.f,0.f,0.f,0.f};
    bool hm = (k > 0), hp = (k < KK-1);
    for (int cc = 0; cc < 32; ++cc) {
        float xm = hm ? vt[k-1][cc] : 0.f;
        float x0 = vt[k][cc];
        float xp = hp ? vt[k+1][cc] : 0.f;
        float4 a0 = *(const float4*)&wl[cc][0][0];
        float4 a1 = *(const float4*)&wl[cc][0][4];
        float4 b0 = *(const float4*)&wl[cc][1][0];
        float4 b1 = *(const float4*)&wl[cc][1][4];
        float4 c0v = *(const float4*)&wl[cc][2][0];
        float4 c1v = *(const float4*)&wl[cc][2][4];
        y[0] = fmaf(xm, a0.x, fmaf(x0, b0.x, fmaf(xp, c0v.x, y[0])));
        y[1] = fmaf(xm, a0.y, fmaf(x0, b0.y, fmaf(xp, c0v.y, y[1])));
        y[2] = fmaf(xm, a0.z, fmaf(x0, b0.z, fmaf(xp, c0v.z, y[2])));
        y[3] = fmaf(xm, a0.w, fmaf(x0, b0.w, fmaf(xp, c0v.w, y[3])));
        y[4] = fmaf(xm, a1.x, fmaf(x0, b1.x, fmaf(xp, c1v.x, y[4])));
        y[5] = fmaf(xm, a1.y, fmaf(x0, b1.y, fmaf(xp, c1v.y, y[5])));
        y[6] = fmaf(xm, a1.z, fmaf(x0, b1.z, fmaf(xp, c1v.z, y[6])));
        y[7] = fmaf(xm, a1.w, fmaf(x0, b1.w, fmaf(xp, c1v.w, y[7])));
    }
    float* pp = part + ((((size_t)(b*2 + ph))*8 + ch)*KK + k)*8;
    *(float4*)&pp[0] = make_float4(y[0],y[1],y[2],y[3]);
    *(float4*)&pp[4] = make_float4(y[4],y[5],y[6],y[7]);
}

// ---------------- k3b: sum chunks + bias + LN + SiLU ----------------
__global__ void k3b(float* __restrict__ ws_, const float* __restrict__ part,
                    const float* __restrict__ wb, const float* __restrict__ wg, const float* __restrict__ wbe,
                    const float* __restrict__ cb, const float* __restrict__ cg, const float* __restrict__ cbe) {
    int b = blockIdx.x, k = threadIdx.x;
#pragma unroll
    for (int ph = 0; ph < 2; ++ph) {
        const float* bias = ph ? cb : wb;
        const float* g    = ph ? cg : wg;
        const float* beta = ph ? cbe : wbe;
        float y[8];
#pragma unroll
        for (int f = 0; f < 8; ++f) y[f] = bias[f];
        for (int ch = 0; ch < 8; ++ch) {
            const float* pp = part + ((((size_t)(b*2 + ph))*8 + ch)*KK + k)*8;
            float4 q0 = *(const float4*)&pp[0];
            float4 q1 = *(const float4*)&pp[4];
            y[0]+=q0.x; y[1]+=q0.y; y[2]+=q0.z; y[3]+=q0.w;
            y[4]+=q1.x; y[5]+=q1.y; y[6]+=q1.z; y[7]+=q1.w;
        }
        float mu = 0.f;
#pragma unroll
        for (int f = 0; f < 8; ++f) mu += y[f];
        mu *= 0.125f;
        float var = 0.f;
#pragma unroll
        for (int f = 0; f < 8; ++f) { float dd = y[f]-mu; var = fmaf(dd, dd, var); }
        var *= 0.125f;
        float inv = rsqrtf(var + 1e-5f);
        float* dst = ws_ + (ph ? OFF_CC : OFF_WC) + (size_t)(b*KK + k)*8;
#pragma unroll
        for (int f = 0; f < 8; ++f) {
            float z = (y[f]-mu)*inv*g[f] + beta[f];
            dst[f] = siluf(z);
        }
    }
}

// ---------------- k4: per-position MLPs + softmax + EIN(bf16) ----------------
__launch_bounds__(256, 3)
__global__ void k4_main(const float* __restrict__ ws, const int* __restrict__ tdur,
                        const float* __restrict__ sw1W, const float* __restrict__ sw1b,
                        const float* __restrict__ sw2W, const float* __restrict__ sw2b,
                        const float* __restrict__ weW, const float* __restrict__ web,
                        const float* __restrict__ sc1W, const float* __restrict__ sc1b,
                        const float* __restrict__ sc2W, const float* __restrict__ sc2b,
                        float* __restrict__ dout, ushort_t* __restrict__ einb) {
    __shared__ float sw1s[160];
    __shared__ float sw1bs[16];
    __shared__ float sc1s[20];
    __shared__ float sc1bs[2];
    __shared__ h2v   sw2h[16][8];
    __shared__ float sw2bias[16];
    __shared__ float wes4[16][4];
    __shared__ float webs[4], sc2s[4], sc2bs[2];
    __shared__ float red[4][4][16];
    __shared__ float gbuf[4][4][4];
    int tid = threadIdx.x;
    int b = blockIdx.y;
    int t0 = blockIdx.x * TPB;
    int lane = tid & 63, wid = tid >> 6;

    if (tid < 160) sw1s[tid] = sw1W[tid];
    if (tid < 16)  { sw1bs[tid] = sw1b[tid]; sw2bias[tid] = sw2b[tid]; }
    if (tid < 20)  sc1s[tid] = sc1W[tid];
    if (tid < 2)   { sc1bs[tid] = sc1b[tid]; sc2bs[tid] = sc2b[tid]; }
    if (tid < 4)   { webs[tid] = web[tid]; sc2s[tid] = sc2W[tid]; }
    if (tid < 128) {
        int j = tid >> 3, ip = tid & 7;
        sw2h[j][ip] = pk(sw2W[(2*ip)*16 + j], sw2W[(2*ip+1)*16 + j]);
    }
    if (tid < 64) wes4[tid>>2][tid&3] = weW[tid];
    __syncthreads();

    int k = tid;
    float s_k = ws[OFF_S + b*KK + k];
    float e_k = ws[OFF_E + b*KK + k];
    float al[16], be[16];
    float lgm[4], p2m[2];
    {
        float wcf[8];
        const float* wp = ws + OFF_WC + (size_t)(b*KK + k)*8;
#pragma unroll
        for (int f = 0; f < 8; ++f) wcf[f] = wp[f];
        float bw[16];
#pragma unroll
        for (int j = 0; j < 16; ++j) {
            float z = sw1bs[j];
#pragma unroll
            for (int f = 0; f < 8; ++f) z = fmaf(wcf[f], sw1s[(2+f)*16 + j], z);
            bw[j] = z;
        }
        h2v h1pm[8];
#pragma unroll
        for (int ip = 0; ip < 8; ++ip)
            h1pm[ip] = pk(siluf(bw[2*ip]), siluf(bw[2*ip+1]));
        lgm[0]=webs[0]; lgm[1]=webs[1]; lgm[2]=webs[2]; lgm[3]=webs[3];
#pragma unroll
        for (int j = 0; j < 16; ++j) {
            const uint4* wpq = (const uint4*)&sw2h[j][0];
            uint4 wa = wpq[0], wb = wpq[1];
            float z = sw2bias[j];
            z = FDOT2(h1pm[0], BC(wa.x), z); z = FDOT2(h1pm[1], BC(wa.y), z);
            z = FDOT2(h1pm[2], BC(wa.z), z); z = FDOT2(h1pm[3], BC(wa.w), z);
            z = FDOT2(h1pm[4], BC(wb.x), z); z = FDOT2(h1pm[5], BC(wb.y), z);
            z = FDOT2(h1pm[6], BC(wb.z), z); z = FDOT2(h1pm[7], BC(wb.w), z);
            float g = siluf(z);
            float4 wv = *(const float4*)&wes4[j][0];
            lgm[0] = fmaf(g, wv.x, lgm[0]); lgm[1] = fmaf(g, wv.y, lgm[1]);
            lgm[2] = fmaf(g, wv.z, lgm[2]); lgm[3] = fmaf(g, wv.w, lgm[3]);
        }
#pragma unroll
        for (int j = 0; j < 16; ++j) {
            float wsj = sw1s[j], wej = sw1s[16 + j];
            be[j] = wsj - wej;
            al[j] = bw[j] - wsj*s_k + wej*e_k;
        }
    }
    float gc[2], dc[2];
    {
        float ccf[8];
        const float* cp = ws + OFF_CC + (size_t)(b*KK + k)*8;
#pragma unroll
        for (int f = 0; f < 8; ++f) ccf[f] = cp[f];
        float bc0 = sc1bs[0], bc1 = sc1bs[1];
#pragma unroll
        for (int f = 0; f < 8; ++f) {
            bc0 = fmaf(ccf[f], sc1s[(2+f)*2 + 0], bc0);
            bc1 = fmaf(ccf[f], sc1s[(2+f)*2 + 1], bc1);
        }
        gc[0] = sc1s[0] - sc1s[2]; gc[1] = sc1s[1] - sc1s[3];
        dc[0] = bc0 - sc1s[0]*s_k + sc1s[2]*e_k;
        dc[1] = bc1 - sc1s[1]*s_k + sc1s[3]*e_k;
        float p1m0 = siluf(bc0), p1m1 = siluf(bc1);
        p2m[0] = siluf(p1m0*sc2s[0] + p1m1*sc2s[2] + sc2bs[0]);
        p2m[1] = siluf(p1m0*sc2s[1] + p1m1*sc2s[3] + sc2bs[1]);
    }
    float sc2r0 = sc2s[0], sc2r1 = sc2s[1], sc2r2 = sc2s[2], sc2r3 = sc2s[3];
    float sc2b0 = sc2bs[0], sc2b1 = sc2bs[1];
    float web0 = webs[0], web1 = webs[1], web2 = webs[2], web3 = webs[3];
    int td = tdur[b];

    for (int tg = 0; tg < TPB; tg += 4) {
        int tbase = t0 + tg;
        h2v h1p[4][8];
        float p2v[4][2];
        float lg[4][4];
        float ex[4][4];
#pragma unroll
        for (int u = 0; u < 4; ++u) {
            float tp1 = (float)(tbase + u + 1);
#pragma unroll
            for (int ip = 0; ip < 8; ++ip) {
                float z0 = siluf(fmaf(tp1, be[2*ip], al[2*ip]));
                float z1 = siluf(fmaf(tp1, be[2*ip+1], al[2*ip+1]));
                h1p[u][ip] = pk(z0, z1);
            }
            float p10 = siluf(fmaf(tp1, gc[0], dc[0]));
            float p11 = siluf(fmaf(tp1, gc[1], dc[1]));
            p2v[u][0] = siluf(p10*sc2r0 + p11*sc2r2 + sc2b0);
            p2v[u][1] = siluf(p10*sc2r1 + p11*sc2r3 + sc2b1);
            lg[u][0]=web0; lg[u][1]=web1; lg[u][2]=web2; lg[u][3]=web3;
        }
#pragma unroll
        for (int j = 0; j < 16; ++j) {
            const uint4* wpq = (const uint4*)&sw2h[j][0];
            uint4 wa = wpq[0], wb = wpq[1];
            h2v w0=BC(wa.x), w1=BC(wa.y), w2=BC(wa.z), w3=BC(wa.w);
            h2v w4_=BC(wb.x), w5=BC(wb.y), w6=BC(wb.z), w7=BC(wb.w);
            float bias = sw2bias[j];
            float4 wv = *(const float4*)&wes4[j][0];
#pragma unroll
            for (int u = 0; u < 4; ++u) {
                float z = bias;
                z = FDOT2(h1p[u][0], w0, z); z = FDOT2(h1p[u][1], w1, z);
                z = FDOT2(h1p[u][2], w2, z); z = FDOT2(h1p[u][3], w3, z);
                z = FDOT2(h1p[u][4], w4_, z); z = FDOT2(h1p[u][5], w5, z);
                z = FDOT2(h1p[u][6], w6, z); z = FDOT2(h1p[u][7], w7, z);
                float g = siluf(z);
                lg[u][0] = fmaf(g, wv.x, lg[u][0]);
                lg[u][1] = fmaf(g, wv.y, lg[u][1]);
                lg[u][2] = fmaf(g, wv.z, lg[u][2]);
                lg[u][3] = fmaf(g, wv.w, lg[u][3]);
            }
        }
#pragma unroll
        for (int u = 0; u < 4; ++u) {
            if ((tbase + u) >= td) {
                lg[u][0]=lgm[0]; lg[u][1]=lgm[1]; lg[u][2]=lgm[2]; lg[u][3]=lgm[3];
                p2v[u][0]=p2m[0]; p2v[u][1]=p2m[1];
            }
        }
#pragma unroll
        for (int u = 0; u < 4; ++u) {
            float m0 = lane63f(rmax64d(lg[u][0]));
            float m1 = lane63f(rmax64d(lg[u][1]));
            float m2 = lane63f(rmax64d(lg[u][2]));
            float m3 = lane63f(rmax64d(lg[u][3]));
            ex[u][0] = __expf(lg[u][0] - m0);
            ex[u][1] = __expf(lg[u][1] - m1);
            ex[u][2] = __expf(lg[u][2] - m2);
            ex[u][3] = __expf(lg[u][3] - m3);
            float s0 = rsum64d(ex[u][0]), s1 = rsum64d(ex[u][1]);
            float s2 = rsum64d(ex[u][2]), s3 = rsum64d(ex[u][3]);
            float u0 = rsum64d(ex[u][0]*p2v[u][0]);
            float u1 = rsum64d(ex[u][0]*p2v[u][1]);
            float u2 = rsum64d(ex[u][1]*p2v[u][0]);
            float u3 = rsum64d(ex[u][1]*p2v[u][1]);
            float u4 = rsum64d(ex[u][2]*p2v[u][0]);
            float u5 = rsum64d(ex[u][2]*p2v[u][1]);
            float u6 = rsum64d(ex[u][3]*p2v[u][0]);
            float u7 = rsum64d(ex[u][3]*p2v[u][1]);
            if (lane == 63) {
                float* rr = &red[u][wid][0];
                *(float4*)&rr[0]  = make_float4(m0, m1, m2, m3);
                *(float4*)&rr[4]  = make_float4(s0, s1, s2, s3);
                *(float4*)&rr[8]  = make_float4(u0, u1, u2, u3);
                *(float4*)&rr[12] = make_float4(u4, u5, u6, u7);
            }
        }
        __syncthreads();
        if (tid < 64) {
            int u = tid >> 4, h = (tid >> 2) & 3, w = tid & 3;
            float m0 = red[u][0][h], m1 = red[u][1][h], m2 = red[u][2][h], m3 = red[u][3][h];
            float M = fmaxf(fmaxf(m0, m1), fmaxf(m2, m3));
            float f0 = __expf(m0 - M), f1 = __expf(m1 - M);
            float f2 = __expf(m2 - M), f3 = __expf(m3 - M);
            float S = red[u][0][4+h]*f0 + red[u][1][4+h]*f1
                    + red[u][2][4+h]*f2 + red[u][3][4+h]*f3;
            float fw = (w == 0) ? f0 : ((w == 1) ? f1 : ((w == 2) ? f2 : f3));
            gbuf[u][w][h] = fw * __builtin_amdgcn_rcpf(S);
        } else if (tid < 96) {
            int idx = tid - 64, u = idx >> 3, j = idx & 7, h = j >> 1;
            float m0 = red[u][0][h], m1 = red[u][1][h], m2 = red[u][2][h], m3 = red[u][3][h];
            float M = fmaxf(fmaxf(m0, m1), fmaxf(m2, m3));
            float f0 = __expf(m0 - M), f1 = __expf(m1 - M);
            float f2 = __expf(m2 - M), f3 = __expf(m3 - M);
            float S = red[u][0][4+h]*f0 + red[u][1][4+h]*f1
                    + red[u][2][4+h]*f2 + red[u][3][4+h]*f3;
            float num = red[u][0][8+j]*f0 + red[u][1][8+j]*f1
                      + red[u][2][8+j]*f2 + red[u][3][8+j]*f3;
            einb[((size_t)b*TT + tbase + u)*32 + j] = f2bf(num * __builtin_amdgcn_rcpf(S));
        } else if (tid < 192) {
            int idx = tid - 96, u = idx / 24, r = idx - u*24;
            einb[((size_t)b*TT + tbase + u)*32 + 8 + r] = 0;
        }
        __syncthreads();
#pragma unroll
        for (int u = 0; u < 4; ++u) {
            int t = tbase + u;
            float4 g4 = *(const float4*)&gbuf[u][wid][0];
            dout[OUT_ATTN + ((size_t)(b*NH + 0)*TT + t)*KK + k] = ex[u][0] * g4.x;
            dout[OUT_ATTN + ((size_t)(b*NH + 1)*TT + t)*KK + k] = ex[u][1] * g4.y;
            dout[OUT_ATTN + ((size_t)(b*NH + 2)*TT + t)*KK + k] = ex[u][2] * g4.z;
            dout[OUT_ATTN + ((size_t)(b*NH + 3)*TT + t)*KK + k] = ex[u][3] * g4.w;
        }
    }
}

// ---------------- kmm: C[m,n] = sum_k A[m,k]*B[n,k] (+bias[n]), f32 out ----------------
#define MLDA 56
__launch_bounds__(256, 2)
__global__ void kmm(const float* __restrict__ A, const float* __restrict__ B,
                    float* __restrict__ C, const float* __restrict__ bias,
                    int Kd, int lda, int ldb, int ldc) {
    int m0 = blockIdx.x * 128, n0 = blockIdx.y * 128;
    __shared__ ushort_t Asl[128*MLDA];
    __shared__ ushort_t Bsl[128*MLDA];
    int tid = threadIdx.x;
    int lane = tid & 63, wid = tid >> 6;
    int wm = wid & 1, wn = wid >> 1;
    int quad = lane >> 4, lo = lane & 15;
    f4v acc[4][4];
#pragma unroll
    for (int i = 0; i < 4; ++i)
#pragma unroll
        for (int j = 0; j < 4; ++j) { f4v zz = {0.f,0.f,0.f,0.f}; acc[i][j] = zz; }
    int srow = tid >> 3;
    int scol = (tid & 7) * 4;
    for (int k0 = 0; k0 < Kd; k0 += 32) {
#pragma unroll
        for (int i = 0; i < 4; ++i) {
            int r = srow + i*32;
            float4 va = *(const float4*)&A[(size_t)(m0 + r)*lda + k0 + scol];
            float4 vb = *(const float4*)&B[(size_t)(n0 + r)*ldb + k0 + scol];
            __hip_bfloat162 pa0 = __float22bfloat162_rn(make_float2(va.x, va.y));
            __hip_bfloat162 pa1 = __float22bfloat162_rn(make_float2(va.z, va.w));
            __hip_bfloat162 pb0 = __float22bfloat162_rn(make_float2(vb.x, vb.y));
            __hip_bfloat162 pb1 = __float22bfloat162_rn(make_float2(vb.z, vb.w));
            *(uint2*)&Asl[r*MLDA + scol] = make_uint2(*(unsigned int*)&pa0, *(unsigned int*)&pa1);
            *(uint2*)&Bsl[r*MLDA + scol] = make_uint2(*(unsigned int*)&pb0, *(unsigned int*)&pb1);
        }
        __syncthreads();
        s8v af[4], bf[4];
#pragma unroll
        for (int mt = 0; mt < 4; ++mt)
            af[mt] = *(const s8v*)&Asl[(wm*64 + mt*16 + lo)*MLDA + quad*8];
#pragma unroll
        for (int nt = 0; nt < 4; ++nt)
            bf[nt] = *(const s8v*)&Bsl[(wn*64 + nt*16 + lo)*MLDA + quad*8];
#pragma unroll
        for (int mt = 0; mt < 4; ++mt)
#pragma unroll
            for (int nt = 0; nt < 4; ++nt)
                acc[mt][nt] = __builtin_amdgcn_mfma_f32_16x16x32_bf16(af[mt], bf[nt], acc[mt][nt], 0, 0, 0);
        __syncthreads();
    }
#pragma unroll
    for (int mt = 0; mt < 4; ++mt)
#pragma unroll
        for (int nt = 0; nt < 4; ++nt) {
            int col = n0 + wn*64 + nt*16 + lo;
            float bv = bias ? bias[col] : 0.f;
#pragma unroll
            for (int r = 0; r < 4; ++r) {
                int row = m0 + wm*64 + mt*16 + quad*4 + r;
                C[(size_t)row*ldc + col] = acc[mt][nt][r] + bv;
            }
        }
}

// ---------------- kmmB: same but bf16 output (U2 build), batched z=(b,h) ----------------
__launch_bounds__(256, 2)
__global__ void kmmB(const float* __restrict__ A, const float* __restrict__ B,
                     ushort_t* __restrict__ C,
                     int Kd, int lda, int ldb, int ldc,
                     long sA2, long sB1, long sB2, long sC1, long sC2, int nz2) {
    int z = blockIdx.z, z1 = z / nz2, z2 = z - z1*nz2;
    A += (size_t)z2*sA2;
    B += (size_t)z1*sB1 + (size_t)z2*sB2;
    C += (size_t)z1*sC1 + (size_t)z2*sC2;
    int m0 = blockIdx.x * 128, n0 = blockIdx.y * 128;
    __shared__ ushort_t Asl[128*MLDA];
    __shared__ ushort_t Bsl[128*MLDA];
    int tid = threadIdx.x;
    int lane = tid & 63, wid = tid >> 6;
    int wm = wid & 1, wn = wid >> 1;
    int quad = lane >> 4, lo = lane & 15;
    f4v acc[4][4];
#pragma unroll
    for (int i = 0; i < 4; ++i)
#pragma unroll
        for (int j = 0; j < 4; ++j) { f4v zz = {0.f,0.f,0.f,0.f}; acc[i][j] = zz; }
    int srow = tid >> 3;
    int scol = (tid & 7) * 4;
    for (int k0 = 0; k0 < Kd; k0 += 32) {
#pragma unroll
        for (int i = 0; i < 4; ++i) {
            int r = srow + i*32;
            float4 va = *(const float4*)&A[(size_t)(m0 + r)*lda + k0 + scol];
            float4 vb = *(const float4*)&B[(size_t)(n0 + r)*ldb + k0 + scol];
            __hip_bfloat162 pa0 = __float22bfloat162_rn(make_float2(va.x, va.y));
            __hip_bfloat162 pa1 = __float22bfloat162_rn(make_float2(va.z, va.w));
            __hip_bfloat162 pb0 = __float22bfloat162_rn(make_float2(vb.x, vb.y));
            __hip_bfloat162 pb1 = __float22bfloat162_rn(make_float2(vb.z, vb.w));
            *(uint2*)&Asl[r*MLDA + scol] = make_uint2(*(unsigned int*)&pa0, *(unsigned int*)&pa1);
            *(uint2*)&Bsl[r*MLDA + scol] = make_uint2(*(unsigned int*)&pb0, *(unsigned int*)&pb1);
        }
        __syncthreads();
        s8v af[4], bf[4];
#pragma unroll
        for (int mt = 0; mt < 4; ++mt)
            af[mt] = *(const s8v*)&Asl[(wm*64 + mt*16 + lo)*MLDA + quad*8];
#pragma unroll
        for (int nt = 0; nt < 4; ++nt)
            bf[nt] = *(const s8v*)&Bsl[(wn*64 + nt*16 + lo)*MLDA + quad*8];
#pragma unroll
        for (int mt = 0; mt < 4; ++mt)
#pragma unroll
            for (int nt = 0; nt < 4; ++nt)
                acc[mt][nt] = __builtin_amdgcn_mfma_f32_16x16x32_bf16(af[mt], bf[nt], acc[mt][nt], 0, 0, 0);
        __syncthreads();
    }
#pragma unroll
    for (int mt = 0; mt < 4; ++mt)
#pragma unroll
        for (int nt = 0; nt < 4; ++nt) {
            int col = n0 + wn*64 + nt*16 + lo;
#pragma unroll
            for (int r = 0; r < 4; ++r) {
                int row = m0 + wm*64 + mt*16 + quad*4 + r;
                C[(size_t)row*ldc + col] = f2bf(acc[mt][nt][r]);
            }
        }
}

// ---------------- kOL2: out = [attn(f32)|EIN(bf16)] @ U2(bf16) + C0 ----------------
__launch_bounds__(256, 2)
__global__ void kOL2(const float* __restrict__ attn, const ushort_t* __restrict__ einb,
                     const ushort_t* __restrict__ U2B, const float* __restrict__ C0,
                     float* __restrict__ out) {
    __shared__ ushort_t Asl[128*MLDA];
    __shared__ ushort_t Bsl[128*MLDA];
    int b = blockIdx.z;
    int t0 = blockIdx.x * 128, c0 = blockIdx.y * 128;
    int tid = threadIdx.x;
    int lane = tid & 63, wid = tid >> 6;
    int wm = wid & 1, wn = wid >> 1;
    int quad = lane >> 4, lo = lane & 15;
    f4v acc[4][4];
#pragma unroll
    for (int i = 0; i < 4; ++i)
#pragma unroll
        for (int j = 0; j < 4; ++j) { f4v zz = {0.f,0.f,0.f,0.f}; acc[i][j] = zz; }
    const float* Ab = attn + (size_t)b*NH*TT*KK;
    const ushort_t* Bb = U2B + (size_t)b*DD*NK2;
    int srow = tid >> 3;
    int scol = (tid & 7) * 4;
    int rB = tid >> 2;
    int cB = (tid & 3) * 8;
    for (int k0 = 0; k0 < NK2; k0 += 32) {
        if (k0 < NH*KK) {
            const float* ag = Ab + ((size_t)((k0 >> 8)*TT + t0))*KK + (k0 & 255);
#pragma unroll
            for (int i = 0; i < 4; ++i) {
                int r = srow + i*32;
                float4 va = *(const float4*)(ag + (size_t)r*KK + scol);
                __hip_bfloat162 pa0 = __float22bfloat162_rn(make_float2(va.x, va.y));
                __hip_bfloat162 pa1 = __float22bfloat162_rn(make_float2(va.z, va.w));
                *(uint2*)&Asl[r*MLDA + scol] = make_uint2(*(unsigned int*)&pa0, *(unsigned int*)&pa1);
            }
        } else {
            const ushort_t* ag = einb + ((size_t)b*TT + t0)*32;
#pragma unroll
            for (int i = 0; i < 2; ++i) {
                int r = rB + i*64;
                uint4 w = *(const uint4*)(ag + (size_t)r*32 + cB);
                *(uint4*)&Asl[r*MLDA + cB] = w;
            }
        }
        {
            const ushort_t* bg = Bb + (size_t)c0*NK2 + k0;
#pragma unroll
            for (int i = 0; i < 2; ++i) {
                int r = rB + i*64;
                uint4 w = *(const uint4*)(bg + (size_t)r*NK2 + cB);
                *(uint4*)&Bsl[r*MLDA + cB] = w;
            }
        }
        __syncthreads();
        s8v af[4], bf[4];
#pragma unroll
        for (int mt = 0; mt < 4; ++mt)
            af[mt] = *(const s8v*)&Asl[(wm*64 + mt*16 + lo)*MLDA + quad*8];
#pragma unroll
        for (int nt = 0; nt < 4; ++nt)
            bf[nt] = *(const s8v*)&Bsl[(wn*64 + nt*16 + lo)*MLDA + quad*8];
#pragma unroll
        for (int mt = 0; mt < 4; ++mt)
#pragma unroll
            for (int nt = 0; nt < 4; ++nt)
                acc[mt][nt] = __builtin_amdgcn_mfma_f32_16x16x32_bf16(af[mt], bf[nt], acc[mt][nt], 0, 0, 0);
        __syncthreads();
    }
#pragma unroll
    for (int mt = 0; mt < 4; ++mt)
#pragma unroll
        for (int nt = 0; nt < 4; ++nt) {
            int col = c0 + wn*64 + nt*16 + lo;
            float bv = C0[col];
#pragma unroll
            for (int r = 0; r < 4; ++r) {
                int row = t0 + wm*64 + mt*16 + quad*4 + r;
                out[((size_t)b*TT + row)*DD + col] = acc[mt][nt][r] + bv;
            }
        }
}

extern "C" void kernel_launch(void* const* d_in, const int* in_sizes, int n_in,
                              void* d_out, int out_size, void* d_ws, size_t ws_size,
                              hipStream_t stream) {
    const float* phs  = (const float*)d_in[0];
    const int*   tdur = (const int*)d_in[2];
    const float* Wd   = (const float*)d_in[4];
    const float* bd   = (const float*)d_in[5];
    const float* W1   = (const float*)d_in[6];
    const float* b1   = (const float*)d_in[7];
    const float* W2   = (const float*)d_in[8];
    const float* b2   = (const float*)d_in[9];
    const float* W3   = (const float*)d_in[10];
    const float* b3   = (const float*)d_in[11];
    const float* wck  = (const float*)d_in[12];
    const float* wcb  = (const float*)d_in[13];
    const float* wlg  = (const float*)d_in[14];
    const float* wlb  = (const float*)d_in[15];
    const float* cck  = (const float*)d_in[16];
    const float* ccb  = (const float*)d_in[17];
    const float* clg  = (const float*)d_in[18];
    const float* clb  = (const float*)d_in[19];
    const float* sw1W = (const float*)d_in[20];
    const float* sw1b = (const float*)d_in[21];
    const float* sw2W = (const float*)d_in[22];
    const float* sw2b = (const float*)d_in[23];
    const float* sc1W = (const float*)d_in[24];
    const float* sc1b = (const float*)d_in[25];
    const float* sc2W = (const float*)d_in[26];
    const float* sc2b = (const float*)d_in[27];
    const float* weW  = (const float*)d_in[28];
    const float* web  = (const float*)d_in[29];
    const float* ceW  = (const float*)d_in[30];
    const float* ceb  = (const float*)d_in[31];

    float* out = (float*)d_out;
    float* ws  = (float*)d_ws;
    ushort_t* U2B  = (ushort_t*)(ws + OFF_U2B);
    ushort_t* EINB = (ushort_t*)(ws + OFF_EINB);

    // 1) prep: W1T, W2T, duration/cumsum, R->U2 tail + C0
    prep<<<48, 256, 0, stream>>>(W1, W2, phs, Wd, bd, ceW, ceb, W3, b3, b2, ws, out);
    // 2) v = phs @ W1 + b1
    kmm<<<dim3(16,2,1), 256, 0, stream>>>(phs, ws + OFF_W1T, ws + OFF_V, b1,
        256, 256, 256, 256);
    // 3) conv features (two-kernel proven form)
    k3a<<<dim3(BB,8,2), 256, 0, stream>>>(ws + OFF_V, wck, cck, ws + OFF_P3);
    k3b<<<BB, 256, 0, stream>>>(ws, ws + OFF_P3, wcb, wlg, wlb, ccb, clg, clb);
    // 4) U2 bf16: U2[b, c, h*256+k] = sum_d W2T[c, h64+d] * v[b, k, h64+d]
    kmmB<<<dim3(2,2,32), 256, 0, stream>>>(ws + OFF_W2T, ws + OFF_V, U2B,
        64, 256, 256, NK2,
        64, (long)KK*DD, 64, (long)DD*NK2, 256, 4);
    // 5) main fused kernel: attn + EIN(bf16)
    k4_main<<<dim3(TT/TPB, BB), 256, 0, stream>>>(ws, tdur, sw1W, sw1b, sw2W, sw2b,
                                                  weW, web, sc1W, sc1b, sc2W, sc2b,
                                                  out, EINB);
    // 6) out = [attn|EIN] @ U2 + C0
    kOL2<<<dim3(TT/128, 2, BB), 256, 0, stream>>>(out + OUT_ATTN, EINB, U2B,
                                                  ws + OFF_C0, out);
}

// Round 9
// 366.595 us; speedup vs baseline: 1.8232x; 1.0257x over previous
//
#include <hip/hip_runtime.h>
#include <hip/hip_bf16.h>
#include <math.h>

#define BB 8
#define KK 256
#define DD 256
#define TT 2048
#define NH 4
#define HD 64
#define FW 8
#define FC 8
#define TPB 8     // t-rows per block in k4 (two groups of 4)
#define NK3 1088  // augmented K for final GEMM: 1024 attn + 64 EIN-pad (8 real)

// workspace float offsets
#define OFF_S    0
#define OFF_E    (OFF_S + BB*KK)                  // 2048
#define OFF_V    (OFF_E + BB*KK)                  // 4096
#define OFF_WC   (OFF_V + BB*KK*DD)               // 528384
#define OFF_CC   (OFF_WC + BB*KK*FW)              // 544768
#define OFF_C0   (OFF_CC + BB*KK*FC)              // 561152
#define OFF_W1T  (OFF_C0 + DD)                    // 561408
#define OFF_W2T  (OFF_W1T + DD*DD)                // 626944
#define OFF_U2B  (OFF_W2T + DD*DD)                // 692480  (bf16: 8 x 256 x 1088 shorts)
#define OFF_EINB (OFF_U2B + BB*DD*NK3/2)          // +1114112 (bf16: 8 x 2048 x 64 shorts)
#define OFF_P3   (OFF_EINB + BB*TT*64/2)          // conv partials, 8x2x8x256x8 f32

// output float offsets (out, d, attn concatenated)
#define OUT_OUT  0
#define OUT_D    (BB*TT*DD)
#define OUT_ATTN (OUT_D + BB*KK)

typedef __attribute__((ext_vector_type(8))) short s8v;
typedef __attribute__((ext_vector_type(4))) float f4v;
typedef __attribute__((ext_vector_type(2))) _Float16 h2v;
typedef unsigned short ushort_t;

#define BC(x) __builtin_bit_cast(h2v, (unsigned int)(x))

__device__ __forceinline__ h2v pk(float a, float b) {
    return __builtin_bit_cast(h2v, __builtin_amdgcn_cvt_pkrtz(a, b));
}
__device__ __forceinline__ ushort_t f2bf(float x) {
    unsigned u = __float_as_uint(x);
    u += 0x7fffu + ((u >> 16) & 1u);
    return (ushort_t)(u >> 16);
}

#if __has_builtin(__builtin_amdgcn_fdot2)
#define FDOT2(a,b,c) __builtin_amdgcn_fdot2((a),(b),(c),false)
#else
__device__ __forceinline__ float FDOT2(h2v a, h2v b, float c) {
    return c + (float)a[0]*(float)b[0] + (float)a[1]*(float)b[1];
}
#endif

__device__ __forceinline__ float siluf(float z) {
    return z * __builtin_amdgcn_rcpf(1.0f + __expf(-z));
}

// ---- pure-DPP wave64 reductions: result in lane 63 ----
__device__ __forceinline__ float rsum64d(float x) {
    x += __int_as_float(__builtin_amdgcn_update_dpp(0, __float_as_int(x), 0x111, 0xf, 0xf, true));
    x += __int_as_float(__builtin_amdgcn_update_dpp(0, __float_as_int(x), 0x112, 0xf, 0xf, true));
    x += __int_as_float(__builtin_amdgcn_update_dpp(0, __float_as_int(x), 0x114, 0xf, 0xf, true));
    x += __int_as_float(__builtin_amdgcn_update_dpp(0, __float_as_int(x), 0x118, 0xf, 0xf, true));
    x += __int_as_float(__builtin_amdgcn_update_dpp(0, __float_as_int(x), 0x142, 0xa, 0xf, true));
    x += __int_as_float(__builtin_amdgcn_update_dpp(0, __float_as_int(x), 0x143, 0xc, 0xf, true));
    return x;
}
__device__ __forceinline__ float rmax64d(float x) {
    const int NI = 0xff800000;
    x = fmaxf(x, __int_as_float(__builtin_amdgcn_update_dpp(NI, __float_as_int(x), 0x111, 0xf, 0xf, false)));
    x = fmaxf(x, __int_as_float(__builtin_amdgcn_update_dpp(NI, __float_as_int(x), 0x112, 0xf, 0xf, false)));
    x = fmaxf(x, __int_as_float(__builtin_amdgcn_update_dpp(NI, __float_as_int(x), 0x114, 0xf, 0xf, false)));
    x = fmaxf(x, __int_as_float(__builtin_amdgcn_update_dpp(NI, __float_as_int(x), 0x118, 0xf, 0xf, false)));
    x = fmaxf(x, __int_as_float(__builtin_amdgcn_update_dpp(NI, __float_as_int(x), 0x142, 0xa, 0xf, false)));
    x = fmaxf(x, __int_as_float(__builtin_amdgcn_update_dpp(NI, __float_as_int(x), 0x143, 0xc, 0xf, false)));
    return x;
}
__device__ __forceinline__ float lane63f(float x) {
    return __int_as_float(__builtin_amdgcn_readlane(__float_as_int(x), 63));
}

// ---------------- prep: {W1T(16), W2T(16), k1(8), R/C0/U2tail(8), einb-zero(64)} ----------------
__launch_bounds__(256)
__global__ void prep(const float* __restrict__ W1, const float* __restrict__ W2,
                     const float* __restrict__ phs, const float* __restrict__ Wd,
                     const float* __restrict__ bd,
                     const float* __restrict__ ceW, const float* __restrict__ ceb,
                     const float* __restrict__ W3, const float* __restrict__ b3,
                     const float* __restrict__ b2,
                     float* __restrict__ ws, float* __restrict__ dout) {
    __shared__ float tl[64][65];
    __shared__ float dbuf[KK];
    int role = blockIdx.x, tid = threadIdx.x;
    if (role < 32) {
        const float* src = (role < 16) ? W1 : W2;
        float* dst = ws + ((role < 16) ? OFF_W1T : OFF_W2T);
        int rr = role & 15;
        int r0 = (rr >> 2)*64, c0 = (rr & 3)*64;
        int rx = tid >> 4, col4 = (tid & 15)*4;
#pragma unroll
        for (int i = 0; i < 4; ++i) {
            int row = rx + i*16;
            float4 vld = *(const float4*)&src[(size_t)(r0+row)*256 + c0 + col4];
            tl[row][col4+0]=vld.x; tl[row][col4+1]=vld.y; tl[row][col4+2]=vld.z; tl[row][col4+3]=vld.w;
        }
        __syncthreads();
#pragma unroll
        for (int i = 0; i < 4; ++i) {
            int row = rx + i*16;
            float4 vst;
            vst.x = tl[col4+0][row]; vst.y = tl[col4+1][row];
            vst.z = tl[col4+2][row]; vst.w = tl[col4+3][row];
            *(float4*)&dst[(size_t)(c0+row)*256 + r0 + col4] = vst;
        }
    } else if (role < 40) {
        int b = role - 32;
        int wave = tid >> 6, lane = tid & 63;
        float4 w4 = ((const float4*)Wd)[lane];
        float bd0 = bd[0];
        for (int kk = 0; kk < 64; ++kk) {
            int k = wave*64 + kk;
            float4 p = ((const float4*)(phs + (size_t)(b*KK + k)*DD))[lane];
            float part = p.x*w4.x + p.y*w4.y + p.z*w4.z + p.w*w4.w;
            float tot = rsum64d(part);
            if (lane == 63) {
                float acc = tot + bd0;
                float dl = fmaxf(acc, 0.f);
                dbuf[k] = fmaxf(expf(dl) - 1.f, 1e-12f);
            }
        }
        __syncthreads();
        int k = tid;
        float dv = dbuf[k];
        for (int off = 1; off < KK; off <<= 1) {
            float t = (k >= off) ? dbuf[k-off] : 0.f;
            __syncthreads();
            dbuf[k] += t;
            __syncthreads();
        }
        float e = dbuf[k];
        dout[OUT_D + b*KK + k] = dv;
        ws[OFF_S + b*KK + k] = e - dv;
        ws[OFF_E + b*KK + k] = e;
    } else if (role < 48) {
        int b = role - 40, c = tid;
        float acc[8] = {0,0,0,0,0,0,0,0};
        float c0v = b3[c] + b2[c];
#pragma unroll 4
        for (int h = 0; h < NH; ++h) {
            for (int d = 0; d < HD; ++d) {
                float w3v = W3[(size_t)(h*HD + d)*DD + c];
                acc[h*2+0] = fmaf(ceW[d],      w3v, acc[h*2+0]);
                acc[h*2+1] = fmaf(ceW[HD + d], w3v, acc[h*2+1]);
                c0v        = fmaf(ceb[d],      w3v, c0v);
            }
        }
        ushort_t* rowp = (ushort_t*)(ws + OFF_U2B) + ((size_t)b*DD + c)*NK3 + 1024;
#pragma unroll
        for (int j = 0; j < 8; ++j) rowp[j] = f2bf(acc[j]);
#pragma unroll
        for (int j = 8; j < 64; ++j) rowp[j] = 0;
        if (b == 0) ws[OFF_C0 + c] = c0v;
    } else {
        // zero einb: 8x2048x64 shorts = 1M shorts over 64 blocks -> 16384 shorts/block
        uint4* ez = (uint4*)((ushort_t*)(ws + OFF_EINB));
        int base = (role - 48) * 2048 + tid;   // in uint4 units (8 shorts each)
#pragma unroll
        for (int i = 0; i < 8; ++i) {
            uint4 z; z.x = 0; z.y = 0; z.z = 0; z.w = 0;
            ez[base + i*256] = z;
        }
    }
}

// ---------------- k3a: conv partials, LDS-staged (proven R6 form) ----------------
__launch_bounds__(256)
__global__ void k3a(const float* __restrict__ vsrc, const float* __restrict__ wk,
                    const float* __restrict__ ck, float* __restrict__ part) {
    __shared__ float vt[KK][33];
    __shared__ float wl[32][3][8];
    int b = blockIdx.x, ch = blockIdx.y, ph = blockIdx.z;
    const float* kern = ph ? ck : wk;
    int tid = threadIdx.x, c0 = ch*32;
    for (int i = tid; i < 768; i += 256) {
        int f = i & 7;
        int cq = i >> 3; int q = cq % 3; int cc = cq / 3;
        wl[cc][q][f] = kern[(f*DD + c0 + cc)*3 + q];
    }
    {
        int cc = tid & 31, r8 = tid >> 5;
        for (int j = 0; j < 32; ++j) {
            int row = r8 + j*8;
            vt[row][cc] = vsrc[(size_t)(b*KK + row)*DD + c0 + cc];
        }
    }
    __syncthreads();
    int k = tid;
    float y[8] = {0.f,0.f,0.f,0.f,0.f,0.f,0.f,0.f};
    bool hm = (k > 0), hp = (k < KK-1);
    for (int cc = 0; cc < 32; ++cc) {
        float xm = hm ? vt[k-1][cc] : 0.f;
        float x0 = vt[k][cc];
        float xp = hp ? vt[k+1][cc] : 0.f;
        float4 a0 = *(const float4*)&wl[cc][0][0];
        float4 a1 = *(const float4*)&wl[cc][0][4];
        float4 b0 = *(const float4*)&wl[cc][1][0];
        float4 b1 = *(const float4*)&wl[cc][1][4];
        float4 c0v = *(const float4*)&wl[cc][2][0];
        float4 c1v = *(const float4*)&wl[cc][2][4];
        y[0] = fmaf(xm, a0.x, fmaf(x0, b0.x, fmaf(xp, c0v.x, y[0])));
        y[1] = fmaf(xm, a0.y, fmaf(x0, b0.y, fmaf(xp, c0v.y, y[1])));
        y[2] = fmaf(xm, a0.z, fmaf(x0, b0.z, fmaf(xp, c0v.z, y[2])));
        y[3] = fmaf(xm, a0.w, fmaf(x0, b0.w, fmaf(xp, c0v.w, y[3])));
        y[4] = fmaf(xm, a1.x, fmaf(x0, b1.x, fmaf(xp, c1v.x, y[4])));
        y[5] = fmaf(xm, a1.y, fmaf(x0, b1.y, fmaf(xp, c1v.y, y[5])));
        y[6] = fmaf(xm, a1.z, fmaf(x0, b1.z, fmaf(xp, c1v.z, y[6])));
        y[7] = fmaf(xm, a1.w, fmaf(x0, b1.w, fmaf(xp, c1v.w, y[7])));
    }
    float* pp = part + ((((size_t)(b*2 + ph))*8 + ch)*KK + k)*8;
    *(float4*)&pp[0] = make_float4(y[0],y[1],y[2],y[3]);
    *(float4*)&pp[4] = make_float4(y[4],y[5],y[6],y[7]);
}

// ---------------- k3b: sum chunks + bias + LN + SiLU ----------------
__global__ void k3b(float* __restrict__ ws_, const float* __restrict__ part,
                    const float* __restrict__ wb, const float* __restrict__ wg, const float* __restrict__ wbe,
                    const float* __restrict__ cb, const float* __restrict__ cg, const float* __restrict__ cbe) {
    int b = blockIdx.x, k = threadIdx.x;
#pragma unroll
    for (int ph = 0; ph < 2; ++ph) {
        const float* bias = ph ? cb : wb;
        const float* g    = ph ? cg : wg;
        const float* beta = ph ? cbe : wbe;
        float y[8];
#pragma unroll
        for (int f = 0; f < 8; ++f) y[f] = bias[f];
        for (int ch = 0; ch < 8; ++ch) {
            const float* pp = part + ((((size_t)(b*2 + ph))*8 + ch)*KK + k)*8;
            float4 q0 = *(const float4*)&pp[0];
            float4 q1 = *(const float4*)&pp[4];
            y[0]+=q0.x; y[1]+=q0.y; y[2]+=q0.z; y[3]+=q0.w;
            y[4]+=q1.x; y[5]+=q1.y; y[6]+=q1.z; y[7]+=q1.w;
        }
        float mu = 0.f;
#pragma unroll
        for (int f = 0; f < 8; ++f) mu += y[f];
        mu *= 0.125f;
        float var = 0.f;
#pragma unroll
        for (int f = 0; f < 8; ++f) { float dd = y[f]-mu; var = fmaf(dd, dd, var); }
        var *= 0.125f;
        float inv = rsqrtf(var + 1e-5f);
        float* dst = ws_ + (ph ? OFF_CC : OFF_WC) + (size_t)(b*KK + k)*8;
#pragma unroll
        for (int f = 0; f < 8; ++f) {
            float z = (y[f]-mu)*inv*g[f] + beta[f];
            dst[f] = siluf(z);
        }
    }
}

// ---------------- k4: per-position MLPs + softmax + EIN(bf16, 64-wide rows) ----------------
__launch_bounds__(256, 3)
__global__ void k4_main(const float* __restrict__ ws, const int* __restrict__ tdur,
                        const float* __restrict__ sw1W, const float* __restrict__ sw1b,
                        const float* __restrict__ sw2W, const float* __restrict__ sw2b,
                        const float* __restrict__ weW, const float* __restrict__ web,
                        const float* __restrict__ sc1W, const float* __restrict__ sc1b,
                        const float* __restrict__ sc2W, const float* __restrict__ sc2b,
                        float* __restrict__ dout, ushort_t* __restrict__ einb) {
    __shared__ float sw1s[160];
    __shared__ float sw1bs[16];
    __shared__ float sc1s[20];
    __shared__ float sc1bs[2];
    __shared__ h2v   sw2h[16][8];
    __shared__ float sw2bias[16];
    __shared__ float wes4[16][4];
    __shared__ float webs[4], sc2s[4], sc2bs[2];
    __shared__ float red[4][4][16];
    __shared__ float gbuf[4][4][4];
    int tid = threadIdx.x;
    int b = blockIdx.y;
    int t0 = blockIdx.x * TPB;
    int lane = tid & 63, wid = tid >> 6;

    if (tid < 160) sw1s[tid] = sw1W[tid];
    if (tid < 16)  { sw1bs[tid] = sw1b[tid]; sw2bias[tid] = sw2b[tid]; }
    if (tid < 20)  sc1s[tid] = sc1W[tid];
    if (tid < 2)   { sc1bs[tid] = sc1b[tid]; sc2bs[tid] = sc2b[tid]; }
    if (tid < 4)   { webs[tid] = web[tid]; sc2s[tid] = sc2W[tid]; }
    if (tid < 128) {
        int j = tid >> 3, ip = tid & 7;
        sw2h[j][ip] = pk(sw2W[(2*ip)*16 + j], sw2W[(2*ip+1)*16 + j]);
    }
    if (tid < 64) wes4[tid>>2][tid&3] = weW[tid];
    __syncthreads();

    int k = tid;
    float s_k = ws[OFF_S + b*KK + k];
    float e_k = ws[OFF_E + b*KK + k];
    float al[16], be[16];
    float lgm[4], p2m[2];
    {
        float wcf[8];
        const float* wp = ws + OFF_WC + (size_t)(b*KK + k)*8;
#pragma unroll
        for (int f = 0; f < 8; ++f) wcf[f] = wp[f];
        float bw[16];
#pragma unroll
        for (int j = 0; j < 16; ++j) {
            float z = sw1bs[j];
#pragma unroll
            for (int f = 0; f < 8; ++f) z = fmaf(wcf[f], sw1s[(2+f)*16 + j], z);
            bw[j] = z;
        }
        h2v h1pm[8];
#pragma unroll
        for (int ip = 0; ip < 8; ++ip)
            h1pm[ip] = pk(siluf(bw[2*ip]), siluf(bw[2*ip+1]));
        lgm[0]=webs[0]; lgm[1]=webs[1]; lgm[2]=webs[2]; lgm[3]=webs[3];
#pragma unroll
        for (int j = 0; j < 16; ++j) {
            const uint4* wpq = (const uint4*)&sw2h[j][0];
            uint4 wa = wpq[0], wb = wpq[1];
            float z = sw2bias[j];
            z = FDOT2(h1pm[0], BC(wa.x), z); z = FDOT2(h1pm[1], BC(wa.y), z);
            z = FDOT2(h1pm[2], BC(wa.z), z); z = FDOT2(h1pm[3], BC(wa.w), z);
            z = FDOT2(h1pm[4], BC(wb.x), z); z = FDOT2(h1pm[5], BC(wb.y), z);
            z = FDOT2(h1pm[6], BC(wb.z), z); z = FDOT2(h1pm[7], BC(wb.w), z);
            float g = siluf(z);
            float4 wv = *(const float4*)&wes4[j][0];
            lgm[0] = fmaf(g, wv.x, lgm[0]); lgm[1] = fmaf(g, wv.y, lgm[1]);
            lgm[2] = fmaf(g, wv.z, lgm[2]); lgm[3] = fmaf(g, wv.w, lgm[3]);
        }
#pragma unroll
        for (int j = 0; j < 16; ++j) {
            float wsj = sw1s[j], wej = sw1s[16 + j];
            be[j] = wsj - wej;
            al[j] = bw[j] - wsj*s_k + wej*e_k;
        }
    }
    float gc[2], dc[2];
    {
        float ccf[8];
        const float* cp = ws + OFF_CC + (size_t)(b*KK + k)*8;
#pragma unroll
        for (int f = 0; f < 8; ++f) ccf[f] = cp[f];
        float bc0 = sc1bs[0], bc1 = sc1bs[1];
#pragma unroll
        for (int f = 0; f < 8; ++f) {
            bc0 = fmaf(ccf[f], sc1s[(2+f)*2 + 0], bc0);
            bc1 = fmaf(ccf[f], sc1s[(2+f)*2 + 1], bc1);
        }
        gc[0] = sc1s[0] - sc1s[2]; gc[1] = sc1s[1] - sc1s[3];
        dc[0] = bc0 - sc1s[0]*s_k + sc1s[2]*e_k;
        dc[1] = bc1 - sc1s[1]*s_k + sc1s[3]*e_k;
        float p1m0 = siluf(bc0), p1m1 = siluf(bc1);
        p2m[0] = siluf(p1m0*sc2s[0] + p1m1*sc2s[2] + sc2bs[0]);
        p2m[1] = siluf(p1m0*sc2s[1] + p1m1*sc2s[3] + sc2bs[1]);
    }
    float sc2r0 = sc2s[0], sc2r1 = sc2s[1], sc2r2 = sc2s[2], sc2r3 = sc2s[3];
    float sc2b0 = sc2bs[0], sc2b1 = sc2bs[1];
    float web0 = webs[0], web1 = webs[1], web2 = webs[2], web3 = webs[3];
    int td = tdur[b];

    for (int tg = 0; tg < TPB; tg += 4) {
        int tbase = t0 + tg;
        h2v h1p[4][8];
        float p2v[4][2];
        float lg[4][4];
        float ex[4][4];
#pragma unroll
        for (int u = 0; u < 4; ++u) {
            float tp1 = (float)(tbase + u + 1);
#pragma unroll
            for (int ip = 0; ip < 8; ++ip) {
                float z0 = siluf(fmaf(tp1, be[2*ip], al[2*ip]));
                float z1 = siluf(fmaf(tp1, be[2*ip+1], al[2*ip+1]));
                h1p[u][ip] = pk(z0, z1);
            }
            float p10 = siluf(fmaf(tp1, gc[0], dc[0]));
            float p11 = siluf(fmaf(tp1, gc[1], dc[1]));
            p2v[u][0] = siluf(p10*sc2r0 + p11*sc2r2 + sc2b0);
            p2v[u][1] = siluf(p10*sc2r1 + p11*sc2r3 + sc2b1);
            lg[u][0]=web0; lg[u][1]=web1; lg[u][2]=web2; lg[u][3]=web3;
        }
#pragma unroll
        for (int j = 0; j < 16; ++j) {
            const uint4* wpq = (const uint4*)&sw2h[j][0];
            uint4 wa = wpq[0], wb = wpq[1];
            h2v w0=BC(wa.x), w1=BC(wa.y), w2=BC(wa.z), w3=BC(wa.w);
            h2v w4_=BC(wb.x), w5=BC(wb.y), w6=BC(wb.z), w7=BC(wb.w);
            float bias = sw2bias[j];
            float4 wv = *(const float4*)&wes4[j][0];
#pragma unroll
            for (int u = 0; u < 4; ++u) {
                float z = bias;
                z = FDOT2(h1p[u][0], w0, z); z = FDOT2(h1p[u][1], w1, z);
                z = FDOT2(h1p[u][2], w2, z); z = FDOT2(h1p[u][3], w3, z);
                z = FDOT2(h1p[u][4], w4_, z); z = FDOT2(h1p[u][5], w5, z);
                z = FDOT2(h1p[u][6], w6, z); z = FDOT2(h1p[u][7], w7, z);
                float g = siluf(z);
                lg[u][0] = fmaf(g, wv.x, lg[u][0]);
                lg[u][1] = fmaf(g, wv.y, lg[u][1]);
                lg[u][2] = fmaf(g, wv.z, lg[u][2]);
                lg[u][3] = fmaf(g, wv.w, lg[u][3]);
            }
        }
#pragma unroll
        for (int u = 0; u < 4; ++u) {
            if ((tbase + u) >= td) {
                lg[u][0]=lgm[0]; lg[u][1]=lgm[1]; lg[u][2]=lgm[2]; lg[u][3]=lgm[3];
                p2v[u][0]=p2m[0]; p2v[u][1]=p2m[1];
            }
        }
#pragma unroll
        for (int u = 0; u < 4; ++u) {
            float m0 = lane63f(rmax64d(lg[u][0]));
            float m1 = lane63f(rmax64d(lg[u][1]));
            float m2 = lane63f(rmax64d(lg[u][2]));
            float m3 = lane63f(rmax64d(lg[u][3]));
            ex[u][0] = __expf(lg[u][0] - m0);
            ex[u][1] = __expf(lg[u][1] - m1);
            ex[u][2] = __expf(lg[u][2] - m2);
            ex[u][3] = __expf(lg[u][3] - m3);
            float s0 = rsum64d(ex[u][0]), s1 = rsum64d(ex[u][1]);
            float s2 = rsum64d(ex[u][2]), s3 = rsum64d(ex[u][3]);
            float u0 = rsum64d(ex[u][0]*p2v[u][0]);
            float u1 = rsum64d(ex[u][0]*p2v[u][1]);
            float u2 = rsum64d(ex[u][1]*p2v[u][0]);
            float u3 = rsum64d(ex[u][1]*p2v[u][1]);
            float u4 = rsum64d(ex[u][2]*p2v[u][0]);
            float u5 = rsum64d(ex[u][2]*p2v[u][1]);
            float u6 = rsum64d(ex[u][3]*p2v[u][0]);
            float u7 = rsum64d(ex[u][3]*p2v[u][1]);
            if (lane == 63) {
                float* rr = &red[u][wid][0];
                *(float4*)&rr[0]  = make_float4(m0, m1, m2, m3);
                *(float4*)&rr[4]  = make_float4(s0, s1, s2, s3);
                *(float4*)&rr[8]  = make_float4(u0, u1, u2, u3);
                *(float4*)&rr[12] = make_float4(u4, u5, u6, u7);
            }
        }
        __syncthreads();
        if (tid < 64) {
            int u = tid >> 4, h = (tid >> 2) & 3, w = tid & 3;
            float m0 = red[u][0][h], m1 = red[u][1][h], m2 = red[u][2][h], m3 = red[u][3][h];
            float M = fmaxf(fmaxf(m0, m1), fmaxf(m2, m3));
            float f0 = __expf(m0 - M), f1 = __expf(m1 - M);
            float f2 = __expf(m2 - M), f3 = __expf(m3 - M);
            float S = red[u][0][4+h]*f0 + red[u][1][4+h]*f1
                    + red[u][2][4+h]*f2 + red[u][3][4+h]*f3;
            float fw = (w == 0) ? f0 : ((w == 1) ? f1 : ((w == 2) ? f2 : f3));
            gbuf[u][w][h] = fw * __builtin_amdgcn_rcpf(S);
        } else if (tid < 96) {
            int idx = tid - 64, u = idx >> 3, j = idx & 7, h = j >> 1;
            float m0 = red[u][0][h], m1 = red[u][1][h], m2 = red[u][2][h], m3 = red[u][3][h];
            float M = fmaxf(fmaxf(m0, m1), fmaxf(m2, m3));
            float f0 = __expf(m0 - M), f1 = __expf(m1 - M);
            float f2 = __expf(m2 - M), f3 = __expf(m3 - M);
            float S = red[u][0][4+h]*f0 + red[u][1][4+h]*f1
                    + red[u][2][4+h]*f2 + red[u][3][4+h]*f3;
            float num = red[u][0][8+j]*f0 + red[u][1][8+j]*f1
                      + red[u][2][8+j]*f2 + red[u][3][8+j]*f3;
            einb[((size_t)b*TT + tbase + u)*64 + j] = f2bf(num * __builtin_amdgcn_rcpf(S));
        }
        __syncthreads();
#pragma unroll
        for (int u = 0; u < 4; ++u) {
            int t = tbase + u;
            float4 g4 = *(const float4*)&gbuf[u][wid][0];
            dout[OUT_ATTN + ((size_t)(b*NH + 0)*TT + t)*KK + k] = ex[u][0] * g4.x;
            dout[OUT_ATTN + ((size_t)(b*NH + 1)*TT + t)*KK + k] = ex[u][1] * g4.y;
            dout[OUT_ATTN + ((size_t)(b*NH + 2)*TT + t)*KK + k] = ex[u][2] * g4.z;
            dout[OUT_ATTN + ((size_t)(b*NH + 3)*TT + t)*KK + k] = ex[u][3] * g4.w;
        }
    }
}

// ---------------- kmm: C[m,n] = sum_k A[m,k]*B[n,k] (+bias[n]), f32 out ----------------
#define MLDA 56
__launch_bounds__(256, 2)
__global__ void kmm(const float* __restrict__ A, const float* __restrict__ B,
                    float* __restrict__ C, const float* __restrict__ bias,
                    int Kd, int lda, int ldb, int ldc) {
    int m0 = blockIdx.x * 128, n0 = blockIdx.y * 128;
    __shared__ ushort_t Asl[128*MLDA];
    __shared__ ushort_t Bsl[128*MLDA];
    int tid = threadIdx.x;
    int lane = tid & 63, wid = tid >> 6;
    int wm = wid & 1, wn = wid >> 1;
    int quad = lane >> 4, lo = lane & 15;
    f4v acc[4][4];
#pragma unroll
    for (int i = 0; i < 4; ++i)
#pragma unroll
        for (int j = 0; j < 4; ++j) { f4v zz = {0.f,0.f,0.f,0.f}; acc[i][j] = zz; }
    int srow = tid >> 3;
    int scol = (tid & 7) * 4;
    for (int k0 = 0; k0 < Kd; k0 += 32) {
#pragma unroll
        for (int i = 0; i < 4; ++i) {
            int r = srow + i*32;
            float4 va = *(const float4*)&A[(size_t)(m0 + r)*lda + k0 + scol];
            float4 vb = *(const float4*)&B[(size_t)(n0 + r)*ldb + k0 + scol];
            __hip_bfloat162 pa0 = __float22bfloat162_rn(make_float2(va.x, va.y));
            __hip_bfloat162 pa1 = __float22bfloat162_rn(make_float2(va.z, va.w));
            __hip_bfloat162 pb0 = __float22bfloat162_rn(make_float2(vb.x, vb.y));
            __hip_bfloat162 pb1 = __float22bfloat162_rn(make_float2(vb.z, vb.w));
            *(uint2*)&Asl[r*MLDA + scol] = make_uint2(*(unsigned int*)&pa0, *(unsigned int*)&pa1);
            *(uint2*)&Bsl[r*MLDA + scol] = make_uint2(*(unsigned int*)&pb0, *(unsigned int*)&pb1);
        }
        __syncthreads();
        s8v af[4], bf[4];
#pragma unroll
        for (int mt = 0; mt < 4; ++mt)
            af[mt] = *(const s8v*)&Asl[(wm*64 + mt*16 + lo)*MLDA + quad*8];
#pragma unroll
        for (int nt = 0; nt < 4; ++nt)
            bf[nt] = *(const s8v*)&Bsl[(wn*64 + nt*16 + lo)*MLDA + quad*8];
#pragma unroll
        for (int mt = 0; mt < 4; ++mt)
#pragma unroll
            for (int nt = 0; nt < 4; ++nt)
                acc[mt][nt] = __builtin_amdgcn_mfma_f32_16x16x32_bf16(af[mt], bf[nt], acc[mt][nt], 0, 0, 0);
        __syncthreads();
    }
#pragma unroll
    for (int mt = 0; mt < 4; ++mt)
#pragma unroll
        for (int nt = 0; nt < 4; ++nt) {
            int col = n0 + wn*64 + nt*16 + lo;
            float bv = bias ? bias[col] : 0.f;
#pragma unroll
            for (int r = 0; r < 4; ++r) {
                int row = m0 + wm*64 + mt*16 + quad*4 + r;
                C[(size_t)row*ldc + col] = acc[mt][nt][r] + bv;
            }
        }
}

// ---------------- kmmB: bf16 output (U2 build), batched z=(b,h) ----------------
__launch_bounds__(256, 2)
__global__ void kmmB(const float* __restrict__ A, const float* __restrict__ B,
                     ushort_t* __restrict__ C,
                     int Kd, int lda, int ldb, int ldc,
                     long sA2, long sB1, long sB2, long sC1, long sC2, int nz2) {
    int z = blockIdx.z, z1 = z / nz2, z2 = z - z1*nz2;
    A += (size_t)z2*sA2;
    B += (size_t)z1*sB1 + (size_t)z2*sB2;
    C += (size_t)z1*sC1 + (size_t)z2*sC2;
    int m0 = blockIdx.x * 128, n0 = blockIdx.y * 128;
    __shared__ ushort_t Asl[128*MLDA];
    __shared__ ushort_t Bsl[128*MLDA];
    int tid = threadIdx.x;
    int lane = tid & 63, wid = tid >> 6;
    int wm = wid & 1, wn = wid >> 1;
    int quad = lane >> 4, lo = lane & 15;
    f4v acc[4][4];
#pragma unroll
    for (int i = 0; i < 4; ++i)
#pragma unroll
        for (int j = 0; j < 4; ++j) { f4v zz = {0.f,0.f,0.f,0.f}; acc[i][j] = zz; }
    int srow = tid >> 3;
    int scol = (tid & 7) * 4;
    for (int k0 = 0; k0 < Kd; k0 += 32) {
#pragma unroll
        for (int i = 0; i < 4; ++i) {
            int r = srow + i*32;
            float4 va = *(const float4*)&A[(size_t)(m0 + r)*lda + k0 + scol];
            float4 vb = *(const float4*)&B[(size_t)(n0 + r)*ldb + k0 + scol];
            __hip_bfloat162 pa0 = __float22bfloat162_rn(make_float2(va.x, va.y));
            __hip_bfloat162 pa1 = __float22bfloat162_rn(make_float2(va.z, va.w));
            __hip_bfloat162 pb0 = __float22bfloat162_rn(make_float2(vb.x, vb.y));
            __hip_bfloat162 pb1 = __float22bfloat162_rn(make_float2(vb.z, vb.w));
            *(uint2*)&Asl[r*MLDA + scol] = make_uint2(*(unsigned int*)&pa0, *(unsigned int*)&pa1);
            *(uint2*)&Bsl[r*MLDA + scol] = make_uint2(*(unsigned int*)&pb0, *(unsigned int*)&pb1);
        }
        __syncthreads();
        s8v af[4], bf[4];
#pragma unroll
        for (int mt = 0; mt < 4; ++mt)
            af[mt] = *(const s8v*)&Asl[(wm*64 + mt*16 + lo)*MLDA + quad*8];
#pragma unroll
        for (int nt = 0; nt < 4; ++nt)
            bf[nt] = *(const s8v*)&Bsl[(wn*64 + nt*16 + lo)*MLDA + quad*8];
#pragma unroll
        for (int mt = 0; mt < 4; ++mt)
#pragma unroll
            for (int nt = 0; nt < 4; ++nt)
                acc[mt][nt] = __builtin_amdgcn_mfma_f32_16x16x32_bf16(af[mt], bf[nt], acc[mt][nt], 0, 0, 0);
        __syncthreads();
    }
#pragma unroll
    for (int mt = 0; mt < 4; ++mt)
#pragma unroll
        for (int nt = 0; nt < 4; ++nt) {
            int col = n0 + wn*64 + nt*16 + lo;
#pragma unroll
            for (int r = 0; r < 4; ++r) {
                int row = m0 + wm*64 + mt*16 + quad*4 + r;
                C[(size_t)row*ldc + col] = f2bf(acc[mt][nt][r]);
            }
        }
}

// ---------------- kOL3: out = [attn(f32)|EIN(bf16)] @ U2(bf16) + C0, 64x128 tile, K-step 64 ----------------
#define OLD 72
__launch_bounds__(256, 4)
__global__ void kOL3(const float* __restrict__ attn, const ushort_t* __restrict__ einb,
                     const ushort_t* __restrict__ U2B, const float* __restrict__ C0,
                     float* __restrict__ out) {
    __shared__ ushort_t Asl[64*OLD];
    __shared__ ushort_t Bsl[128*OLD];
    int b = blockIdx.z;
    int t0 = blockIdx.x * 64, c0 = blockIdx.y * 128;
    int tid = threadIdx.x;
    int lane = tid & 63, wid = tid >> 6;
    int wm = wid & 1, wn = wid >> 1;
    int quad = lane >> 4, lo = lane & 15;
    f4v acc[2][4];
#pragma unroll
    for (int i = 0; i < 2; ++i)
#pragma unroll
        for (int j = 0; j < 4; ++j) { f4v zz = {0.f,0.f,0.f,0.f}; acc[i][j] = zz; }
    const float* Ab = attn + (size_t)b*NH*TT*KK;
    const ushort_t* Bb = U2B + (size_t)b*DD*NK3;
    int rA = tid >> 2, cA = (tid & 3) * 16;   // A: 64 rows x 64 elems
    int rB = tid >> 1, cB = (tid & 1) * 32;   // B: 128 rows x 64 shorts
    for (int k0 = 0; k0 < NK3; k0 += 64) {
        if (k0 < NH*KK) {
            const float* ag = Ab + ((size_t)((k0 >> 8)*TT + t0 + rA))*KK + (k0 & 255) + cA;
#pragma unroll
            for (int i = 0; i < 4; ++i) {
                float4 va = *(const float4*)(ag + i*4);
                __hip_bfloat162 p0 = __float22bfloat162_rn(make_float2(va.x, va.y));
                __hip_bfloat162 p1 = __float22bfloat162_rn(make_float2(va.z, va.w));
                *(uint2*)&Asl[rA*OLD + cA + i*4] = make_uint2(*(unsigned int*)&p0, *(unsigned int*)&p1);
            }
        } else {
            const ushort_t* ag = einb + ((size_t)b*TT + t0 + rA)*64 + cA;
#pragma unroll
            for (int i = 0; i < 2; ++i)
                *(uint4*)&Asl[rA*OLD + cA + i*8] = *(const uint4*)(ag + i*8);
        }
        {
            const ushort_t* bg = Bb + (size_t)(c0 + rB)*NK3 + k0 + cB;
#pragma unroll
            for (int i = 0; i < 4; ++i)
                *(uint4*)&Bsl[rB*OLD + cB + i*8] = *(const uint4*)(bg + i*8);
        }
        __syncthreads();
        s8v af[2][2], bf[4][2];
#pragma unroll
        for (int mt = 0; mt < 2; ++mt)
#pragma unroll
            for (int ks = 0; ks < 2; ++ks)
                af[mt][ks] = *(const s8v*)&Asl[(wm*32 + mt*16 + lo)*OLD + ks*32 + quad*8];
#pragma unroll
        for (int nt = 0; nt < 4; ++nt)
#pragma unroll
            for (int ks = 0; ks < 2; ++ks)
                bf[nt][ks] = *(const s8v*)&Bsl[(wn*64 + nt*16 + lo)*OLD + ks*32 + quad*8];
#pragma unroll
        for (int mt = 0; mt < 2; ++mt)
#pragma unroll
            for (int nt = 0; nt < 4; ++nt)
#pragma unroll
                for (int ks = 0; ks < 2; ++ks)
                    acc[mt][nt] = __builtin_amdgcn_mfma_f32_16x16x32_bf16(af[mt][ks], bf[nt][ks], acc[mt][nt], 0, 0, 0);
        __syncthreads();
    }
#pragma unroll
    for (int mt = 0; mt < 2; ++mt)
#pragma unroll
        for (int nt = 0; nt < 4; ++nt) {
            int col = c0 + wn*64 + nt*16 + lo;
            float bv = C0[col];
#pragma unroll
            for (int r = 0; r < 4; ++r) {
                int row = t0 + wm*32 + mt*16 + quad*4 + r;
                out[((size_t)b*TT + row)*DD + col] = acc[mt][nt][r] + bv;
            }
        }
}

extern "C" void kernel_launch(void* const* d_in, const int* in_sizes, int n_in,
                              void* d_out, int out_size, void* d_ws, size_t ws_size,
                              hipStream_t stream) {
    const float* phs  = (const float*)d_in[0];
    const int*   tdur = (const int*)d_in[2];
    const float* Wd   = (const float*)d_in[4];
    const float* bd   = (const float*)d_in[5];
    const float* W1   = (const float*)d_in[6];
    const float* b1   = (const float*)d_in[7];
    const float* W2   = (const float*)d_in[8];
    const float* b2   = (const float*)d_in[9];
    const float* W3   = (const float*)d_in[10];
    const float* b3   = (const float*)d_in[11];
    const float* wck  = (const float*)d_in[12];
    const float* wcb  = (const float*)d_in[13];
    const float* wlg  = (const float*)d_in[14];
    const float* wlb  = (const float*)d_in[15];
    const float* cck  = (const float*)d_in[16];
    const float* ccb  = (const float*)d_in[17];
    const float* clg  = (const float*)d_in[18];
    const float* clb  = (const float*)d_in[19];
    const float* sw1W = (const float*)d_in[20];
    const float* sw1b = (const float*)d_in[21];
    const float* sw2W = (const float*)d_in[22];
    const float* sw2b = (const float*)d_in[23];
    const float* sc1W = (const float*)d_in[24];
    const float* sc1b = (const float*)d_in[25];
    const float* sc2W = (const float*)d_in[26];
    const float* sc2b = (const float*)d_in[27];
    const float* weW  = (const float*)d_in[28];
    const float* web  = (const float*)d_in[29];
    const float* ceW  = (const float*)d_in[30];
    const float* ceb  = (const float*)d_in[31];

    float* out = (float*)d_out;
    float* ws  = (float*)d_ws;
    ushort_t* U2B  = (ushort_t*)(ws + OFF_U2B);
    ushort_t* EINB = (ushort_t*)(ws + OFF_EINB);

    // 1) prep: W1T, W2T, duration/cumsum, R->U2 tail + C0, einb zero
    prep<<<112, 256, 0, stream>>>(W1, W2, phs, Wd, bd, ceW, ceb, W3, b3, b2, ws, out);
    // 2) v = phs @ W1 + b1
    kmm<<<dim3(16,2,1), 256, 0, stream>>>(phs, ws + OFF_W1T, ws + OFF_V, b1,
        256, 256, 256, 256);
    // 3) conv features
    k3a<<<dim3(BB,8,2), 256, 0, stream>>>(ws + OFF_V, wck, cck, ws + OFF_P3);
    k3b<<<BB, 256, 0, stream>>>(ws, ws + OFF_P3, wcb, wlg, wlb, ccb, clg, clb);
    // 4) U2 bf16: U2[b, c, h*256+k] = sum_d W2T[c, h64+d] * v[b, k, h64+d]
    kmmB<<<dim3(2,2,32), 256, 0, stream>>>(ws + OFF_W2T, ws + OFF_V, U2B,
        64, 256, 256, NK3,
        64, (long)KK*DD, 64, (long)DD*NK3, 256, 4);
    // 5) main fused kernel: attn + EIN(bf16)
    k4_main<<<dim3(TT/TPB, BB), 256, 0, stream>>>(ws, tdur, sw1W, sw1b, sw2W, sw2b,
                                                  weW, web, sc1W, sc1b, sc2W, sc2b,
                                                  out, EINB);
    // 6) out = [attn|EIN] @ U2 + C0
    kOL3<<<dim3(TT/64, 2, BB), 256, 0, stream>>>(out + OUT_ATTN, EINB, U2B,
                                                 ws + OFF_C0, out);
}

// Round 10
// 357.899 us; speedup vs baseline: 1.8675x; 1.0243x over previous
//
#include <hip/hip_runtime.h>
#include <hip/hip_bf16.h>
#include <math.h>

#define BB 8
#define KK 256
#define DD 256
#define TT 2048
#define NH 4
#define HD 64
#define FW 8
#define FC 8
#define TPB 8     // t-rows per block in k4 (two groups of 4)
#define NK3 1088  // augmented K: 1024 attn + 64 EIN-pad (8 real)

// workspace float offsets
#define OFF_S    0
#define OFF_E    (OFF_S + BB*KK)                  // 2048
#define OFF_V    (OFF_E + BB*KK)                  // 4096
#define OFF_WC   (OFF_V + BB*KK*DD)               // 528384
#define OFF_CC   (OFF_WC + BB*KK*FW)              // 544768
#define OFF_C0   (OFF_CC + BB*KK*FC)              // 561152
#define OFF_W1T  (OFF_C0 + DD)                    // 561408
#define OFF_W2T  (OFF_W1T + DD*DD)                // 626944
#define OFF_U2B  (OFF_W2T + DD*DD)                // 692480   (bf16: 8 x 256 x 1088)
#define OFF_ATB  (OFF_U2B + BB*DD*NK3/2)          // 1806592  (bf16: 8 x 2048 x 1088, attn|EIN)
#define OFF_P3   (OFF_ATB + BB*TT*NK3/2)          // 10719488 (conv partials)
// total: 10981632 floats = 43.9 MB (ws evidence: ~56 MB poison traffic)

// output float offsets (out, d, attn concatenated)
#define OUT_OUT  0
#define OUT_D    (BB*TT*DD)
#define OUT_ATTN (OUT_D + BB*KK)

typedef __attribute__((ext_vector_type(8))) short s8v;
typedef __attribute__((ext_vector_type(4))) float f4v;
typedef __attribute__((ext_vector_type(2))) _Float16 h2v;
typedef unsigned short ushort_t;

#define BC(x) __builtin_bit_cast(h2v, (unsigned int)(x))

__device__ __forceinline__ h2v pk(float a, float b) {
    return __builtin_bit_cast(h2v, __builtin_amdgcn_cvt_pkrtz(a, b));
}
__device__ __forceinline__ ushort_t f2bf(float x) {
    unsigned u = __float_as_uint(x);
    u += 0x7fffu + ((u >> 16) & 1u);
    return (ushort_t)(u >> 16);
}

#if __has_builtin(__builtin_amdgcn_fdot2)
#define FDOT2(a,b,c) __builtin_amdgcn_fdot2((a),(b),(c),false)
#else
__device__ __forceinline__ float FDOT2(h2v a, h2v b, float c) {
    return c + (float)a[0]*(float)b[0] + (float)a[1]*(float)b[1];
}
#endif

__device__ __forceinline__ float siluf(float z) {
    return z * __builtin_amdgcn_rcpf(1.0f + __expf(-z));
}

// ---- pure-DPP wave64 reductions: result in lane 63 ----
__device__ __forceinline__ float rsum64d(float x) {
    x += __int_as_float(__builtin_amdgcn_update_dpp(0, __float_as_int(x), 0x111, 0xf, 0xf, true));
    x += __int_as_float(__builtin_amdgcn_update_dpp(0, __float_as_int(x), 0x112, 0xf, 0xf, true));
    x += __int_as_float(__builtin_amdgcn_update_dpp(0, __float_as_int(x), 0x114, 0xf, 0xf, true));
    x += __int_as_float(__builtin_amdgcn_update_dpp(0, __float_as_int(x), 0x118, 0xf, 0xf, true));
    x += __int_as_float(__builtin_amdgcn_update_dpp(0, __float_as_int(x), 0x142, 0xa, 0xf, true));
    x += __int_as_float(__builtin_amdgcn_update_dpp(0, __float_as_int(x), 0x143, 0xc, 0xf, true));
    return x;
}
__device__ __forceinline__ float rmax64d(float x) {
    const int NI = 0xff800000;
    x = fmaxf(x, __int_as_float(__builtin_amdgcn_update_dpp(NI, __float_as_int(x), 0x111, 0xf, 0xf, false)));
    x = fmaxf(x, __int_as_float(__builtin_amdgcn_update_dpp(NI, __float_as_int(x), 0x112, 0xf, 0xf, false)));
    x = fmaxf(x, __int_as_float(__builtin_amdgcn_update_dpp(NI, __float_as_int(x), 0x114, 0xf, 0xf, false)));
    x = fmaxf(x, __int_as_float(__builtin_amdgcn_update_dpp(NI, __float_as_int(x), 0x118, 0xf, 0xf, false)));
    x = fmaxf(x, __int_as_float(__builtin_amdgcn_update_dpp(NI, __float_as_int(x), 0x142, 0xa, 0xf, false)));
    x = fmaxf(x, __int_as_float(__builtin_amdgcn_update_dpp(NI, __float_as_int(x), 0x143, 0xc, 0xf, false)));
    return x;
}
__device__ __forceinline__ float lane63f(float x) {
    return __int_as_float(__builtin_amdgcn_readlane(__float_as_int(x), 63));
}

// ---------------- prep: {W1T(16), W2T(16), k1(8), R/C0/U2tail(8), ATB-tail-zero(64)} ----------------
__launch_bounds__(256)
__global__ void prep(const float* __restrict__ W1, const float* __restrict__ W2,
                     const float* __restrict__ phs, const float* __restrict__ Wd,
                     const float* __restrict__ bd,
                     const float* __restrict__ ceW, const float* __restrict__ ceb,
                     const float* __restrict__ W3, const float* __restrict__ b3,
                     const float* __restrict__ b2,
                     float* __restrict__ ws, float* __restrict__ dout) {
    __shared__ float tl[64][65];
    __shared__ float dbuf[KK];
    int role = blockIdx.x, tid = threadIdx.x;
    if (role < 32) {
        const float* src = (role < 16) ? W1 : W2;
        float* dst = ws + ((role < 16) ? OFF_W1T : OFF_W2T);
        int rr = role & 15;
        int r0 = (rr >> 2)*64, c0 = (rr & 3)*64;
        int rx = tid >> 4, col4 = (tid & 15)*4;
#pragma unroll
        for (int i = 0; i < 4; ++i) {
            int row = rx + i*16;
            float4 vld = *(const float4*)&src[(size_t)(r0+row)*256 + c0 + col4];
            tl[row][col4+0]=vld.x; tl[row][col4+1]=vld.y; tl[row][col4+2]=vld.z; tl[row][col4+3]=vld.w;
        }
        __syncthreads();
#pragma unroll
        for (int i = 0; i < 4; ++i) {
            int row = rx + i*16;
            float4 vst;
            vst.x = tl[col4+0][row]; vst.y = tl[col4+1][row];
            vst.z = tl[col4+2][row]; vst.w = tl[col4+3][row];
            *(float4*)&dst[(size_t)(c0+row)*256 + r0 + col4] = vst;
        }
    } else if (role < 40) {
        int b = role - 32;
        int wave = tid >> 6, lane = tid & 63;
        float4 w4 = ((const float4*)Wd)[lane];
        float bd0 = bd[0];
        for (int kk = 0; kk < 64; ++kk) {
            int k = wave*64 + kk;
            float4 p = ((const float4*)(phs + (size_t)(b*KK + k)*DD))[lane];
            float part = p.x*w4.x + p.y*w4.y + p.z*w4.z + p.w*w4.w;
            float tot = rsum64d(part);
            if (lane == 63) {
                float acc = tot + bd0;
                float dl = fmaxf(acc, 0.f);
                dbuf[k] = fmaxf(expf(dl) - 1.f, 1e-12f);
            }
        }
        __syncthreads();
        int k = tid;
        float dv = dbuf[k];
        for (int off = 1; off < KK; off <<= 1) {
            float t = (k >= off) ? dbuf[k-off] : 0.f;
            __syncthreads();
            dbuf[k] += t;
            __syncthreads();
        }
        float e = dbuf[k];
        dout[OUT_D + b*KK + k] = dv;
        ws[OFF_S + b*KK + k] = e - dv;
        ws[OFF_E + b*KK + k] = e;
    } else if (role < 48) {
        int b = role - 40, c = tid;
        float acc[8] = {0,0,0,0,0,0,0,0};
        float c0v = b3[c] + b2[c];
#pragma unroll 4
        for (int h = 0; h < NH; ++h) {
            for (int d = 0; d < HD; ++d) {
                float w3v = W3[(size_t)(h*HD + d)*DD + c];
                acc[h*2+0] = fmaf(ceW[d],      w3v, acc[h*2+0]);
                acc[h*2+1] = fmaf(ceW[HD + d], w3v, acc[h*2+1]);
                c0v        = fmaf(ceb[d],      w3v, c0v);
            }
        }
        ushort_t* rowp = (ushort_t*)(ws + OFF_U2B) + ((size_t)b*DD + c)*NK3 + 1024;
#pragma unroll
        for (int j = 0; j < 8; ++j) rowp[j] = f2bf(acc[j]);
#pragma unroll
        for (int j = 8; j < 64; ++j) rowp[j] = 0;
        if (b == 0) ws[OFF_C0 + c] = c0v;
    } else {
        // zero ATB tail cols 1024..1087 for 16384 (b,t) rows; 64 blocks, 1 row/thread
        int row = (role - 48) * 256 + tid;
        ushort_t* rp = (ushort_t*)(ws + OFF_ATB) + (size_t)row*NK3 + 1024;
        uint4 z; z.x = 0; z.y = 0; z.z = 0; z.w = 0;
#pragma unroll
        for (int i = 0; i < 8; ++i) *(uint4*)(rp + i*8) = z;
    }
}

// ---------------- k3a: conv partials, LDS-staged ----------------
__launch_bounds__(256)
__global__ void k3a(const float* __restrict__ vsrc, const float* __restrict__ wk,
                    const float* __restrict__ ck, float* __restrict__ part) {
    __shared__ float vt[KK][33];
    __shared__ float wl[32][3][8];
    int b = blockIdx.x, ch = blockIdx.y, ph = blockIdx.z;
    const float* kern = ph ? ck : wk;
    int tid = threadIdx.x, c0 = ch*32;
    for (int i = tid; i < 768; i += 256) {
        int f = i & 7;
        int cq = i >> 3; int q = cq % 3; int cc = cq / 3;
        wl[cc][q][f] = kern[(f*DD + c0 + cc)*3 + q];
    }
    {
        int cc = tid & 31, r8 = tid >> 5;
        for (int j = 0; j < 32; ++j) {
            int row = r8 + j*8;
            vt[row][cc] = vsrc[(size_t)(b*KK + row)*DD + c0 + cc];
        }
    }
    __syncthreads();
    int k = tid;
    float y[8] = {0.f,0.f,0.f,0.f,0.f,0.f,0.f,0.f};
    bool hm = (k > 0), hp = (k < KK-1);
    for (int cc = 0; cc < 32; ++cc) {
        float xm = hm ? vt[k-1][cc] : 0.f;
        float x0 = vt[k][cc];
        float xp = hp ? vt[k+1][cc] : 0.f;
        float4 a0 = *(const float4*)&wl[cc][0][0];
        float4 a1 = *(const float4*)&wl[cc][0][4];
        float4 b0 = *(const float4*)&wl[cc][1][0];
        float4 b1 = *(const float4*)&wl[cc][1][4];
        float4 c0v = *(const float4*)&wl[cc][2][0];
        float4 c1v = *(const float4*)&wl[cc][2][4];
        y[0] = fmaf(xm, a0.x, fmaf(x0, b0.x, fmaf(xp, c0v.x, y[0])));
        y[1] = fmaf(xm, a0.y, fmaf(x0, b0.y, fmaf(xp, c0v.y, y[1])));
        y[2] = fmaf(xm, a0.z, fmaf(x0, b0.z, fmaf(xp, c0v.z, y[2])));
        y[3] = fmaf(xm, a0.w, fmaf(x0, b0.w, fmaf(xp, c0v.w, y[3])));
        y[4] = fmaf(xm, a1.x, fmaf(x0, b1.x, fmaf(xp, c1v.x, y[4])));
        y[5] = fmaf(xm, a1.y, fmaf(x0, b1.y, fmaf(xp, c1v.y, y[5])));
        y[6] = fmaf(xm, a1.z, fmaf(x0, b1.z, fmaf(xp, c1v.z, y[6])));
        y[7] = fmaf(xm, a1.w, fmaf(x0, b1.w, fmaf(xp, c1v.w, y[7])));
    }
    float* pp = part + ((((size_t)(b*2 + ph))*8 + ch)*KK + k)*8;
    *(float4*)&pp[0] = make_float4(y[0],y[1],y[2],y[3]);
    *(float4*)&pp[4] = make_float4(y[4],y[5],y[6],y[7]);
}

// ---------------- k4: per-position MLPs + softmax + attn(f32+bf16) + EIN ----------------
__launch_bounds__(256, 3)
__global__ void k4_main(const float* __restrict__ ws, const int* __restrict__ tdur,
                        const float* __restrict__ sw1W, const float* __restrict__ sw1b,
                        const float* __restrict__ sw2W, const float* __restrict__ sw2b,
                        const float* __restrict__ weW, const float* __restrict__ web,
                        const float* __restrict__ sc1W, const float* __restrict__ sc1b,
                        const float* __restrict__ sc2W, const float* __restrict__ sc2b,
                        float* __restrict__ dout, ushort_t* __restrict__ atb) {
    __shared__ float sw1s[160];
    __shared__ float sw1bs[16];
    __shared__ float sc1s[20];
    __shared__ float sc1bs[2];
    __shared__ h2v   sw2h[16][8];
    __shared__ float sw2bias[16];
    __shared__ float wes4[16][4];
    __shared__ float webs[4], sc2s[4], sc2bs[2];
    __shared__ float red[4][4][16];
    __shared__ float gbuf[4][4][4];
    int tid = threadIdx.x;
    int b = blockIdx.y;
    int t0 = blockIdx.x * TPB;
    int lane = tid & 63, wid = tid >> 6;

    if (tid < 160) sw1s[tid] = sw1W[tid];
    if (tid < 16)  { sw1bs[tid] = sw1b[tid]; sw2bias[tid] = sw2b[tid]; }
    if (tid < 20)  sc1s[tid] = sc1W[tid];
    if (tid < 2)   { sc1bs[tid] = sc1b[tid]; sc2bs[tid] = sc2b[tid]; }
    if (tid < 4)   { webs[tid] = web[tid]; sc2s[tid] = sc2W[tid]; }
    if (tid < 128) {
        int j = tid >> 3, ip = tid & 7;
        sw2h[j][ip] = pk(sw2W[(2*ip)*16 + j], sw2W[(2*ip+1)*16 + j]);
    }
    if (tid < 64) wes4[tid>>2][tid&3] = weW[tid];
    __syncthreads();

    int k = tid;
    float s_k = ws[OFF_S + b*KK + k];
    float e_k = ws[OFF_E + b*KK + k];
    float al[16], be[16];
    float lgm[4], p2m[2];
    {
        float wcf[8];
        const float* wp = ws + OFF_WC + (size_t)(b*KK + k)*8;
#pragma unroll
        for (int f = 0; f < 8; ++f) wcf[f] = wp[f];
        float bw[16];
#pragma unroll
        for (int j = 0; j < 16; ++j) {
            float z = sw1bs[j];
#pragma unroll
            for (int f = 0; f < 8; ++f) z = fmaf(wcf[f], sw1s[(2+f)*16 + j], z);
            bw[j] = z;
        }
        h2v h1pm[8];
#pragma unroll
        for (int ip = 0; ip < 8; ++ip)
            h1pm[ip] = pk(siluf(bw[2*ip]), siluf(bw[2*ip+1]));
        lgm[0]=webs[0]; lgm[1]=webs[1]; lgm[2]=webs[2]; lgm[3]=webs[3];
#pragma unroll
        for (int j = 0; j < 16; ++j) {
            const uint4* wpq = (const uint4*)&sw2h[j][0];
            uint4 wa = wpq[0], wb = wpq[1];
            float z = sw2bias[j];
            z = FDOT2(h1pm[0], BC(wa.x), z); z = FDOT2(h1pm[1], BC(wa.y), z);
            z = FDOT2(h1pm[2], BC(wa.z), z); z = FDOT2(h1pm[3], BC(wa.w), z);
            z = FDOT2(h1pm[4], BC(wb.x), z); z = FDOT2(h1pm[5], BC(wb.y), z);
            z = FDOT2(h1pm[6], BC(wb.z), z); z = FDOT2(h1pm[7], BC(wb.w), z);
            float g = siluf(z);
            float4 wv = *(const float4*)&wes4[j][0];
            lgm[0] = fmaf(g, wv.x, lgm[0]); lgm[1] = fmaf(g, wv.y, lgm[1]);
            lgm[2] = fmaf(g, wv.z, lgm[2]); lgm[3] = fmaf(g, wv.w, lgm[3]);
        }
#pragma unroll
        for (int j = 0; j < 16; ++j) {
            float wsj = sw1s[j], wej = sw1s[16 + j];
            be[j] = wsj - wej;
            al[j] = bw[j] - wsj*s_k + wej*e_k;
        }
    }
    float gc[2], dc[2];
    {
        float ccf[8];
        const float* cp = ws + OFF_CC + (size_t)(b*KK + k)*8;
#pragma unroll
        for (int f = 0; f < 8; ++f) ccf[f] = cp[f];
        float bc0 = sc1bs[0], bc1 = sc1bs[1];
#pragma unroll
        for (int f = 0; f < 8; ++f) {
            bc0 = fmaf(ccf[f], sc1s[(2+f)*2 + 0], bc0);
            bc1 = fmaf(ccf[f], sc1s[(2+f)*2 + 1], bc1);
        }
        gc[0] = sc1s[0] - sc1s[2]; gc[1] = sc1s[1] - sc1s[3];
        dc[0] = bc0 - sc1s[0]*s_k + sc1s[2]*e_k;
        dc[1] = bc1 - sc1s[1]*s_k + sc1s[3]*e_k;
        float p1m0 = siluf(bc0), p1m1 = siluf(bc1);
        p2m[0] = siluf(p1m0*sc2s[0] + p1m1*sc2s[2] + sc2bs[0]);
        p2m[1] = siluf(p1m0*sc2s[1] + p1m1*sc2s[3] + sc2bs[1]);
    }
    float sc2r0 = sc2s[0], sc2r1 = sc2s[1], sc2r2 = sc2s[2], sc2r3 = sc2s[3];
    float sc2b0 = sc2bs[0], sc2b1 = sc2bs[1];
    float web0 = webs[0], web1 = webs[1], web2 = webs[2], web3 = webs[3];
    int td = tdur[b];

    for (int tg = 0; tg < TPB; tg += 4) {
        int tbase = t0 + tg;
        h2v h1p[4][8];
        float p2v[4][2];
        float lg[4][4];
        float ex[4][4];
#pragma unroll
        for (int u = 0; u < 4; ++u) {
            float tp1 = (float)(tbase + u + 1);
#pragma unroll
            for (int ip = 0; ip < 8; ++ip) {
                float z0 = siluf(fmaf(tp1, be[2*ip], al[2*ip]));
                float z1 = siluf(fmaf(tp1, be[2*ip+1], al[2*ip+1]));
                h1p[u][ip] = pk(z0, z1);
            }
            float p10 = siluf(fmaf(tp1, gc[0], dc[0]));
            float p11 = siluf(fmaf(tp1, gc[1], dc[1]));
            p2v[u][0] = siluf(p10*sc2r0 + p11*sc2r2 + sc2b0);
            p2v[u][1] = siluf(p10*sc2r1 + p11*sc2r3 + sc2b1);
            lg[u][0]=web0; lg[u][1]=web1; lg[u][2]=web2; lg[u][3]=web3;
        }
#pragma unroll
        for (int j = 0; j < 16; ++j) {
            const uint4* wpq = (const uint4*)&sw2h[j][0];
            uint4 wa = wpq[0], wb = wpq[1];
            h2v w0=BC(wa.x), w1=BC(wa.y), w2=BC(wa.z), w3=BC(wa.w);
            h2v w4_=BC(wb.x), w5=BC(wb.y), w6=BC(wb.z), w7=BC(wb.w);
            float bias = sw2bias[j];
            float4 wv = *(const float4*)&wes4[j][0];
#pragma unroll
            for (int u = 0; u < 4; ++u) {
                float z = bias;
                z = FDOT2(h1p[u][0], w0, z); z = FDOT2(h1p[u][1], w1, z);
                z = FDOT2(h1p[u][2], w2, z); z = FDOT2(h1p[u][3], w3, z);
                z = FDOT2(h1p[u][4], w4_, z); z = FDOT2(h1p[u][5], w5, z);
                z = FDOT2(h1p[u][6], w6, z); z = FDOT2(h1p[u][7], w7, z);
                float g = siluf(z);
                lg[u][0] = fmaf(g, wv.x, lg[u][0]);
                lg[u][1] = fmaf(g, wv.y, lg[u][1]);
                lg[u][2] = fmaf(g, wv.z, lg[u][2]);
                lg[u][3] = fmaf(g, wv.w, lg[u][3]);
            }
        }
#pragma unroll
        for (int u = 0; u < 4; ++u) {
            if ((tbase + u) >= td) {
                lg[u][0]=lgm[0]; lg[u][1]=lgm[1]; lg[u][2]=lgm[2]; lg[u][3]=lgm[3];
                p2v[u][0]=p2m[0]; p2v[u][1]=p2m[1];
            }
        }
#pragma unroll
        for (int u = 0; u < 4; ++u) {
            float m0 = lane63f(rmax64d(lg[u][0]));
            float m1 = lane63f(rmax64d(lg[u][1]));
            float m2 = lane63f(rmax64d(lg[u][2]));
            float m3 = lane63f(rmax64d(lg[u][3]));
            ex[u][0] = __expf(lg[u][0] - m0);
            ex[u][1] = __expf(lg[u][1] - m1);
            ex[u][2] = __expf(lg[u][2] - m2);
            ex[u][3] = __expf(lg[u][3] - m3);
            float s0 = rsum64d(ex[u][0]), s1 = rsum64d(ex[u][1]);
            float s2 = rsum64d(ex[u][2]), s3 = rsum64d(ex[u][3]);
            float u0 = rsum64d(ex[u][0]*p2v[u][0]);
            float u1 = rsum64d(ex[u][0]*p2v[u][1]);
            float u2 = rsum64d(ex[u][1]*p2v[u][0]);
            float u3 = rsum64d(ex[u][1]*p2v[u][1]);
            float u4 = rsum64d(ex[u][2]*p2v[u][0]);
            float u5 = rsum64d(ex[u][2]*p2v[u][1]);
            float u6 = rsum64d(ex[u][3]*p2v[u][0]);
            float u7 = rsum64d(ex[u][3]*p2v[u][1]);
            if (lane == 63) {
                float* rr = &red[u][wid][0];
                *(float4*)&rr[0]  = make_float4(m0, m1, m2, m3);
                *(float4*)&rr[4]  = make_float4(s0, s1, s2, s3);
                *(float4*)&rr[8]  = make_float4(u0, u1, u2, u3);
                *(float4*)&rr[12] = make_float4(u4, u5, u6, u7);
            }
        }
        __syncthreads();
        if (tid < 64) {
            int u = tid >> 4, h = (tid >> 2) & 3, w = tid & 3;
            float m0 = red[u][0][h], m1 = red[u][1][h], m2 = red[u][2][h], m3 = red[u][3][h];
            float M = fmaxf(fmaxf(m0, m1), fmaxf(m2, m3));
            float f0 = __expf(m0 - M), f1 = __expf(m1 - M);
            float f2 = __expf(m2 - M), f3 = __expf(m3 - M);
            float S = red[u][0][4+h]*f0 + red[u][1][4+h]*f1
                    + red[u][2][4+h]*f2 + red[u][3][4+h]*f3;
            float fw = (w == 0) ? f0 : ((w == 1) ? f1 : ((w == 2) ? f2 : f3));
            gbuf[u][w][h] = fw * __builtin_amdgcn_rcpf(S);
        } else if (tid < 96) {
            int idx = tid - 64, u = idx >> 3, j = idx & 7, h = j >> 1;
            float m0 = red[u][0][h], m1 = red[u][1][h], m2 = red[u][2][h], m3 = red[u][3][h];
            float M = fmaxf(fmaxf(m0, m1), fmaxf(m2, m3));
            float f0 = __expf(m0 - M), f1 = __expf(m1 - M);
            float f2 = __expf(m2 - M), f3 = __expf(m3 - M);
            float S = red[u][0][4+h]*f0 + red[u][1][4+h]*f1
                    + red[u][2][4+h]*f2 + red[u][3][4+h]*f3;
            float num = red[u][0][8+j]*f0 + red[u][1][8+j]*f1
                      + red[u][2][8+j]*f2 + red[u][3][8+j]*f3;
            atb[((size_t)b*TT + tbase + u)*NK3 + 1024 + j] = f2bf(num * __builtin_amdgcn_rcpf(S));
        }
        __syncthreads();
#pragma unroll
        for (int u = 0; u < 4; ++u) {
            int t = tbase + u;
            float4 g4 = *(const float4*)&gbuf[u][wid][0];
            float a0 = ex[u][0] * g4.x, a1 = ex[u][1] * g4.y;
            float a2 = ex[u][2] * g4.z, a3 = ex[u][3] * g4.w;
            dout[OUT_ATTN + ((size_t)(b*NH + 0)*TT + t)*KK + k] = a0;
            dout[OUT_ATTN + ((size_t)(b*NH + 1)*TT + t)*KK + k] = a1;
            dout[OUT_ATTN + ((size_t)(b*NH + 2)*TT + t)*KK + k] = a2;
            dout[OUT_ATTN + ((size_t)(b*NH + 3)*TT + t)*KK + k] = a3;
            ushort_t* ap = atb + ((size_t)b*TT + t)*NK3 + k;
            ap[0]   = f2bf(a0);
            ap[256] = f2bf(a1);
            ap[512] = f2bf(a2);
            ap[768] = f2bf(a3);
        }
    }
}

// ---------------- kmm: C[m,n] = sum_k A[m,k]*B[n,k] (+bias[n]), f32 out ----------------
#define MLDA 56
__launch_bounds__(256, 2)
__global__ void kmm(const float* __restrict__ A, const float* __restrict__ B,
                    float* __restrict__ C, const float* __restrict__ bias,
                    int Kd, int lda, int ldb, int ldc) {
    int m0 = blockIdx.x * 128, n0 = blockIdx.y * 128;
    __shared__ ushort_t Asl[128*MLDA];
    __shared__ ushort_t Bsl[128*MLDA];
    int tid = threadIdx.x;
    int lane = tid & 63, wid = tid >> 6;
    int wm = wid & 1, wn = wid >> 1;
    int quad = lane >> 4, lo = lane & 15;
    f4v acc[4][4];
#pragma unroll
    for (int i = 0; i < 4; ++i)
#pragma unroll
        for (int j = 0; j < 4; ++j) { f4v zz = {0.f,0.f,0.f,0.f}; acc[i][j] = zz; }
    int srow = tid >> 3;
    int scol = (tid & 7) * 4;
    for (int k0 = 0; k0 < Kd; k0 += 32) {
#pragma unroll
        for (int i = 0; i < 4; ++i) {
            int r = srow + i*32;
            float4 va = *(const float4*)&A[(size_t)(m0 + r)*lda + k0 + scol];
            float4 vb = *(const float4*)&B[(size_t)(n0 + r)*ldb + k0 + scol];
            __hip_bfloat162 pa0 = __float22bfloat162_rn(make_float2(va.x, va.y));
            __hip_bfloat162 pa1 = __float22bfloat162_rn(make_float2(va.z, va.w));
            __hip_bfloat162 pb0 = __float22bfloat162_rn(make_float2(vb.x, vb.y));
            __hip_bfloat162 pb1 = __float22bfloat162_rn(make_float2(vb.z, vb.w));
            *(uint2*)&Asl[r*MLDA + scol] = make_uint2(*(unsigned int*)&pa0, *(unsigned int*)&pa1);
            *(uint2*)&Bsl[r*MLDA + scol] = make_uint2(*(unsigned int*)&pb0, *(unsigned int*)&pb1);
        }
        __syncthreads();
        s8v af[4], bf[4];
#pragma unroll
        for (int mt = 0; mt < 4; ++mt)
            af[mt] = *(const s8v*)&Asl[(wm*64 + mt*16 + lo)*MLDA + quad*8];
#pragma unroll
        for (int nt = 0; nt < 4; ++nt)
            bf[nt] = *(const s8v*)&Bsl[(wn*64 + nt*16 + lo)*MLDA + quad*8];
#pragma unroll
        for (int mt = 0; mt < 4; ++mt)
#pragma unroll
            for (int nt = 0; nt < 4; ++nt)
                acc[mt][nt] = __builtin_amdgcn_mfma_f32_16x16x32_bf16(af[mt], bf[nt], acc[mt][nt], 0, 0, 0);
        __syncthreads();
    }
#pragma unroll
    for (int mt = 0; mt < 4; ++mt)
#pragma unroll
        for (int nt = 0; nt < 4; ++nt) {
            int col = n0 + wn*64 + nt*16 + lo;
            float bv = bias ? bias[col] : 0.f;
#pragma unroll
            for (int r = 0; r < 4; ++r) {
                int row = m0 + wm*64 + mt*16 + quad*4 + r;
                C[(size_t)row*ldc + col] = acc[mt][nt][r] + bv;
            }
        }
}

// ---------------- kmmB: U2 bf16 build (z<32) + fused k3b (z>=32) ----------------
__launch_bounds__(256, 2)
__global__ void kmmB(const float* __restrict__ A, const float* __restrict__ B,
                     ushort_t* __restrict__ C,
                     int Kd, int lda, int ldb, int ldc,
                     long sA2, long sB1, long sB2, long sC1, long sC2, int nz2,
                     float* __restrict__ ws_, const float* __restrict__ part,
                     const float* __restrict__ wb, const float* __restrict__ wg,
                     const float* __restrict__ wbe,
                     const float* __restrict__ cb, const float* __restrict__ cg,
                     const float* __restrict__ cbe) {
    if (blockIdx.z >= 32) {
        // fused k3b: sum chunks + bias + LN + SiLU
        if (blockIdx.x != 0 || blockIdx.y != 0) return;
        int b = blockIdx.z - 32, k = threadIdx.x;
#pragma unroll
        for (int ph = 0; ph < 2; ++ph) {
            const float* bias = ph ? cb : wb;
            const float* g    = ph ? cg : wg;
            const float* beta = ph ? cbe : wbe;
            float y[8];
#pragma unroll
            for (int f = 0; f < 8; ++f) y[f] = bias[f];
            for (int ch = 0; ch < 8; ++ch) {
                const float* pp = part + ((((size_t)(b*2 + ph))*8 + ch)*KK + k)*8;
                float4 q0 = *(const float4*)&pp[0];
                float4 q1 = *(const float4*)&pp[4];
                y[0]+=q0.x; y[1]+=q0.y; y[2]+=q0.z; y[3]+=q0.w;
                y[4]+=q1.x; y[5]+=q1.y; y[6]+=q1.z; y[7]+=q1.w;
            }
            float mu = 0.f;
#pragma unroll
            for (int f = 0; f < 8; ++f) mu += y[f];
            mu *= 0.125f;
            float var = 0.f;
#pragma unroll
            for (int f = 0; f < 8; ++f) { float dd = y[f]-mu; var = fmaf(dd, dd, var); }
            var *= 0.125f;
            float inv = rsqrtf(var + 1e-5f);
            float* dst = ws_ + (ph ? OFF_CC : OFF_WC) + (size_t)(b*KK + k)*8;
#pragma unroll
            for (int f = 0; f < 8; ++f) {
                float z = (y[f]-mu)*inv*g[f] + beta[f];
                dst[f] = siluf(z);
            }
        }
        return;
    }
    int z = blockIdx.z, z1 = z / nz2, z2 = z - z1*nz2;
    A += (size_t)z2*sA2;
    B += (size_t)z1*sB1 + (size_t)z2*sB2;
    C += (size_t)z1*sC1 + (size_t)z2*sC2;
    int m0 = blockIdx.x * 128, n0 = blockIdx.y * 128;
    __shared__ ushort_t Asl[128*MLDA];
    __shared__ ushort_t Bsl[128*MLDA];
    int tid = threadIdx.x;
    int lane = tid & 63, wid = tid >> 6;
    int wm = wid & 1, wn = wid >> 1;
    int quad = lane >> 4, lo = lane & 15;
    f4v acc[4][4];
#pragma unroll
    for (int i = 0; i < 4; ++i)
#pragma unroll
        for (int j = 0; j < 4; ++j) { f4v zz = {0.f,0.f,0.f,0.f}; acc[i][j] = zz; }
    int srow = tid >> 3;
    int scol = (tid & 7) * 4;
    for (int k0 = 0; k0 < Kd; k0 += 32) {
#pragma unroll
        for (int i = 0; i < 4; ++i) {
            int r = srow + i*32;
            float4 va = *(const float4*)&A[(size_t)(m0 + r)*lda + k0 + scol];
            float4 vb = *(const float4*)&B[(size_t)(n0 + r)*ldb + k0 + scol];
            __hip_bfloat162 pa0 = __float22bfloat162_rn(make_float2(va.x, va.y));
            __hip_bfloat162 pa1 = __float22bfloat162_rn(make_float2(va.z, va.w));
            __hip_bfloat162 pb0 = __float22bfloat162_rn(make_float2(vb.x, vb.y));
            __hip_bfloat162 pb1 = __float22bfloat162_rn(make_float2(vb.z, vb.w));
            *(uint2*)&Asl[r*MLDA + scol] = make_uint2(*(unsigned int*)&pa0, *(unsigned int*)&pa1);
            *(uint2*)&Bsl[r*MLDA + scol] = make_uint2(*(unsigned int*)&pb0, *(unsigned int*)&pb1);
        }
        __syncthreads();
        s8v af[4], bf[4];
#pragma unroll
        for (int mt = 0; mt < 4; ++mt)
            af[mt] = *(const s8v*)&Asl[(wm*64 + mt*16 + lo)*MLDA + quad*8];
#pragma unroll
        for (int nt = 0; nt < 4; ++nt)
            bf[nt] = *(const s8v*)&Bsl[(wn*64 + nt*16 + lo)*MLDA + quad*8];
#pragma unroll
        for (int mt = 0; mt < 4; ++mt)
#pragma unroll
            for (int nt = 0; nt < 4; ++nt)
                acc[mt][nt] = __builtin_amdgcn_mfma_f32_16x16x32_bf16(af[mt], bf[nt], acc[mt][nt], 0, 0, 0);
        __syncthreads();
    }
#pragma unroll
    for (int mt = 0; mt < 4; ++mt)
#pragma unroll
        for (int nt = 0; nt < 4; ++nt) {
            int col = n0 + wn*64 + nt*16 + lo;
#pragma unroll
            for (int r = 0; r < 4; ++r) {
                int row = m0 + wm*64 + mt*16 + quad*4 + r;
                C[(size_t)row*ldc + col] = f2bf(acc[mt][nt][r]);
            }
        }
}

// ---------------- kOL3: out = ATB(bf16) @ U2(bf16) + C0, 64x128 tile, K-step 64 ----------------
#define OLD 72
__launch_bounds__(256, 4)
__global__ void kOL3(const ushort_t* __restrict__ atb,
                     const ushort_t* __restrict__ U2B, const float* __restrict__ C0,
                     float* __restrict__ out) {
    __shared__ ushort_t Asl[64*OLD];
    __shared__ ushort_t Bsl[128*OLD];
    int b = blockIdx.z;
    int t0 = blockIdx.x * 64, c0 = blockIdx.y * 128;
    int tid = threadIdx.x;
    int lane = tid & 63, wid = tid >> 6;
    int wm = wid & 1, wn = wid >> 1;
    int quad = lane >> 4, lo = lane & 15;
    f4v acc[2][4];
#pragma unroll
    for (int i = 0; i < 2; ++i)
#pragma unroll
        for (int j = 0; j < 4; ++j) { f4v zz = {0.f,0.f,0.f,0.f}; acc[i][j] = zz; }
    const ushort_t* Ab = atb + (size_t)b*TT*NK3;
    const ushort_t* Bb = U2B + (size_t)b*DD*NK3;
    int rA = tid >> 2, cA = (tid & 3) * 16;   // A: 64 rows x 64 shorts
    int rB = tid >> 1, cB = (tid & 1) * 32;   // B: 128 rows x 64 shorts
    for (int k0 = 0; k0 < NK3; k0 += 64) {
        {
            const ushort_t* ag = Ab + (size_t)(t0 + rA)*NK3 + k0 + cA;
            *(uint4*)&Asl[rA*OLD + cA]     = *(const uint4*)(ag);
            *(uint4*)&Asl[rA*OLD + cA + 8] = *(const uint4*)(ag + 8);
        }
        {
            const ushort_t* bg = Bb + (size_t)(c0 + rB)*NK3 + k0 + cB;
#pragma unroll
            for (int i = 0; i < 4; ++i)
                *(uint4*)&Bsl[rB*OLD + cB + i*8] = *(const uint4*)(bg + i*8);
        }
        __syncthreads();
        s8v af[2][2], bf[4][2];
#pragma unroll
        for (int mt = 0; mt < 2; ++mt)
#pragma unroll
            for (int ks = 0; ks < 2; ++ks)
                af[mt][ks] = *(const s8v*)&Asl[(wm*32 + mt*16 + lo)*OLD + ks*32 + quad*8];
#pragma unroll
        for (int nt = 0; nt < 4; ++nt)
#pragma unroll
            for (int ks = 0; ks < 2; ++ks)
                bf[nt][ks] = *(const s8v*)&Bsl[(wn*64 + nt*16 + lo)*OLD + ks*32 + quad*8];
#pragma unroll
        for (int mt = 0; mt < 2; ++mt)
#pragma unroll
            for (int nt = 0; nt < 4; ++nt)
#pragma unroll
                for (int ks = 0; ks < 2; ++ks)
                    acc[mt][nt] = __builtin_amdgcn_mfma_f32_16x16x32_bf16(af[mt][ks], bf[nt][ks], acc[mt][nt], 0, 0, 0);
        __syncthreads();
    }
#pragma unroll
    for (int mt = 0; mt < 2; ++mt)
#pragma unroll
        for (int nt = 0; nt < 4; ++nt) {
            int col = c0 + wn*64 + nt*16 + lo;
            float bv = C0[col];
#pragma unroll
            for (int r = 0; r < 4; ++r) {
                int row = t0 + wm*32 + mt*16 + quad*4 + r;
                out[((size_t)b*TT + row)*DD + col] = acc[mt][nt][r] + bv;
            }
        }
}

extern "C" void kernel_launch(void* const* d_in, const int* in_sizes, int n_in,
                              void* d_out, int out_size, void* d_ws, size_t ws_size,
                              hipStream_t stream) {
    const float* phs  = (const float*)d_in[0];
    const int*   tdur = (const int*)d_in[2];
    const float* Wd   = (const float*)d_in[4];
    const float* bd   = (const float*)d_in[5];
    const float* W1   = (const float*)d_in[6];
    const float* b1   = (const float*)d_in[7];
    const float* W2   = (const float*)d_in[8];
    const float* b2   = (const float*)d_in[9];
    const float* W3   = (const float*)d_in[10];
    const float* b3   = (const float*)d_in[11];
    const float* wck  = (const float*)d_in[12];
    const float* wcb  = (const float*)d_in[13];
    const float* wlg  = (const float*)d_in[14];
    const float* wlb  = (const float*)d_in[15];
    const float* cck  = (const float*)d_in[16];
    const float* ccb  = (const float*)d_in[17];
    const float* clg  = (const float*)d_in[18];
    const float* clb  = (const float*)d_in[19];
    const float* sw1W = (const float*)d_in[20];
    const float* sw1b = (const float*)d_in[21];
    const float* sw2W = (const float*)d_in[22];
    const float* sw2b = (const float*)d_in[23];
    const float* sc1W = (const float*)d_in[24];
    const float* sc1b = (const float*)d_in[25];
    const float* sc2W = (const float*)d_in[26];
    const float* sc2b = (const float*)d_in[27];
    const float* weW  = (const float*)d_in[28];
    const float* web  = (const float*)d_in[29];
    const float* ceW  = (const float*)d_in[30];
    const float* ceb  = (const float*)d_in[31];

    float* out = (float*)d_out;
    float* ws  = (float*)d_ws;
    ushort_t* U2B = (ushort_t*)(ws + OFF_U2B);
    ushort_t* ATB = (ushort_t*)(ws + OFF_ATB);

    // 1) prep: W1T, W2T, duration/cumsum, R->U2 tail + C0, ATB tail zero
    prep<<<112, 256, 0, stream>>>(W1, W2, phs, Wd, bd, ceW, ceb, W3, b3, b2, ws, out);
    // 2) v = phs @ W1 + b1
    kmm<<<dim3(16,2,1), 256, 0, stream>>>(phs, ws + OFF_W1T, ws + OFF_V, b1,
        256, 256, 256, 256);
    // 3) conv partials
    k3a<<<dim3(BB,8,2), 256, 0, stream>>>(ws + OFF_V, wck, cck, ws + OFF_P3);
    // 4) U2 bf16 (z<32) + fused k3b (z>=32)
    kmmB<<<dim3(2,2,40), 256, 0, stream>>>(ws + OFF_W2T, ws + OFF_V, U2B,
        64, 256, 256, NK3,
        64, (long)KK*DD, 64, (long)DD*NK3, 256, 4,
        ws, ws + OFF_P3, wcb, wlg, wlb, ccb, clg, clb);
    // 5) main fused kernel: attn f32 + attn/EIN bf16
    k4_main<<<dim3(TT/TPB, BB), 256, 0, stream>>>(ws, tdur, sw1W, sw1b, sw2W, sw2b,
                                                  weW, web, sc1W, sc1b, sc2W, sc2b,
                                                  out, ATB);
    // 6) out = ATB @ U2 + C0
    kOL3<<<dim3(TT/64, 2, BB), 256, 0, stream>>>(ATB, U2B, ws + OFF_C0, out);
}